// Round 5
// baseline (1083.561 us; speedup 1.0000x reference)
//
#include <hip/hip_runtime.h>
#include <hip/hip_bf16.h>

typedef unsigned short u16;
using short8 = __attribute__((ext_vector_type(8))) short;
using half8  = __attribute__((ext_vector_type(8))) _Float16;
using half4  = __attribute__((ext_vector_type(4))) _Float16;
using half2v = __attribute__((ext_vector_type(2))) _Float16;
using f32x4  = __attribute__((ext_vector_type(4))) float;
using f32x16 = __attribute__((ext_vector_type(16))) float;

__device__ __forceinline__ u16 f2bf(float f) {
    unsigned int u = __float_as_uint(f);
    u += 0x7FFFu + ((u >> 16) & 1u);   // RNE
    return (u16)(u >> 16);
}
__device__ __forceinline__ float bf2f(u16 h) {
    return __uint_as_float(((unsigned int)h) << 16);
}

__device__ __forceinline__ void gl_lds16(const void* g, void* l) {
    __builtin_amdgcn_global_load_lds((const __attribute__((address_space(1))) void*)g,
                                     (__attribute__((address_space(3))) void*)l, 16, 0, 0);
}

#define PIPE_WAIT8() asm volatile("s_waitcnt vmcnt(8)" ::: "memory")
#define PIPE_WAIT0() asm volatile("s_waitcnt vmcnt(0)" ::: "memory")
#define BAR() __builtin_amdgcn_s_barrier()

// ---------------- weight prep: conv2 HWIO -> [kk][n][ci], split bf16 hi/lo ----------------
__global__ __launch_bounds__(256) void wprep_split_kernel(const float* __restrict__ src,
                                                          u16* __restrict__ hi, u16* __restrict__ lo) {
    int idx = blockIdx.x * 256 + threadIdx.x;          // 16*256*256
    int ci = idx & 255, n = (idx >> 8) & 255, kk = idx >> 16;
    float v = src[(kk * 256 + ci) * 256 + n];
    u16 h = f2bf(v);
    hi[idx] = h;
    lo[idx] = f2bf(v - bf2f(h));
}

// ---------------- weight prep: deconv1 parity-combined -> [tap_g][n][ci] fp16 (25 taps) ----------------
__global__ __launch_bounds__(256) void wprep_dc1_par(const float* __restrict__ src, _Float16* __restrict__ dst) {
    const int idx = blockIdx.x * 256 + threadIdx.x;    // 25*65536
    const int ci = idx & 255, n = (idx >> 8) & 255, tg = idx >> 16;
    int p, j;
    if (tg < 9)       { p = 0; j = tg; }
    else if (tg < 15) { p = 1; j = tg - 9; }
    else if (tg < 21) { p = 2; j = tg - 15; }
    else              { p = 3; j = tg - 21; }
    const int dy = p >> 1, dx = p & 1;
    const int nx = 3 - dx;
    const int oyi = j / nx, oxi = j % nx;
    int ky0, kyn, kx0, kxn;
    if (dy == 0) { ky0 = (oyi == 0) ? 0 : (oyi == 1 ? 1 : 3); kyn = (oyi == 1) ? 2 : 1; }
    else         { ky0 = (oyi == 0) ? 0 : 2;                  kyn = 2; }
    if (dx == 0) { kx0 = (oxi == 0) ? 0 : (oxi == 1 ? 1 : 3); kxn = (oxi == 1) ? 2 : 1; }
    else         { kx0 = (oxi == 0) ? 0 : 2;                  kxn = 2; }
    float s = 0.f;
    for (int a = 0; a < kyn; ++a)
        for (int c = 0; c < kxn; ++c)
            s += src[(((ky0 + a) * 4 + (kx0 + c)) * 256 + ci) * 256 + n];
    dst[((size_t)tg << 16) + (n << 8) + ci] = (_Float16)s;
}

// ---------------- weight prep: deconv2 parity-combined -> [p][9][256] fp16 (zero-padded taps) ----------------
__global__ __launch_bounds__(256) void wprep_dc2_par(const float* __restrict__ src, _Float16* __restrict__ dst) {
    const int idx = blockIdx.x * 256 + threadIdx.x;    // 36*256 = 9216
    if (idx >= 9216) return;
    const int ci = idx & 255;
    const int j9 = (idx >> 8) % 9, p = (idx >> 8) / 9;
    const int dy = p >> 1, dx = p & 1;
    const int oyi = j9 / 3, oxi = j9 % 3;
    float s = 0.f;
    if (!((dy == 1 && oyi == 2) || (dx == 1 && oxi == 2))) {
        int ky0, kyn, kx0, kxn;
        if (dy == 0) { ky0 = (oyi == 0) ? 0 : (oyi == 1 ? 1 : 3); kyn = (oyi == 1) ? 2 : 1; }
        else         { ky0 = (oyi == 0) ? 0 : 2;                  kyn = 2; }
        if (dx == 0) { kx0 = (oxi == 0) ? 0 : (oxi == 1 ? 1 : 3); kxn = (oxi == 1) ? 2 : 1; }
        else         { kx0 = (oxi == 0) ? 0 : 2;                  kxn = 2; }
        for (int a = 0; a < kyn; ++a)
            for (int c = 0; c < kxn; ++c)
                s += src[((ky0 + a) * 4 + (kx0 + c)) * 256 + ci];
    }
    dst[idx] = (_Float16)s;
}

// ---------------- conv1 (1->256) + ReLU + maxpool, block = (b, pooled row) ----------------
__global__ __launch_bounds__(256) void conv1_pool_v2(const float* __restrict__ x,
                                                     const float* __restrict__ w,
                                                     const float* __restrict__ bias,
                                                     u16* __restrict__ hi, u16* __restrict__ lo) {
    __shared__ float xs[5][32];
    const int blk = blockIdx.x;                         // b*14 + py
    const int py = blk % 14, b = blk / 14;
    const int t = threadIdx.x;
    for (int i = t; i < 160; i += 256) {
        const int r = i >> 5, c = i & 31;
        const int gy = 2 * py - 1 + r, gx = c - 1;
        float v = 0.f;
        if ((unsigned)gy < 28u && (unsigned)gx < 28u) v = x[(b * 28 + gy) * 28 + gx];
        xs[r][c] = v;
    }
    __syncthreads();
    float wr[16];
#pragma unroll
    for (int k = 0; k < 16; ++k) wr[k] = w[k * 256 + t];
    const float bs = bias[t];
    for (int px = 0; px < 14; ++px) {
        float m = 0.f;
#pragma unroll
        for (int dy = 0; dy < 2; ++dy)
#pragma unroll
            for (int dx = 0; dx < 2; ++dx) {
                float a = bs;
#pragma unroll
                for (int ky = 0; ky < 4; ++ky)
#pragma unroll
                    for (int kx = 0; kx < 4; ++kx)
                        a += xs[dy + ky][2 * px + dx + kx] * wr[ky * 4 + kx];
                m = fmaxf(m, a);
            }
        u16 h = f2bf(m);
        const int o = ((b * 14 + py) * 14 + px) * 256 + t;
        hi[o] = h;
        lo[o] = f2bf(m - bf2f(h));
    }
}

// ---------------- conv2 v4: 128x128 tile, 2-buffer counted-vmcnt, 32x32x16 split-bf16 3-pass ----------------
// M = 50176, N = 256, K = 16 x 256. Grid (392, 2). LDS rows: [hi 64B | lo 64B], XOR(row&7) chunk swizzle.
__global__ __launch_bounds__(256, 2) void conv2_split_v4(const u16* __restrict__ Ih, const u16* __restrict__ Il,
                                                         const u16* __restrict__ Wh, const u16* __restrict__ Wl,
                                                         const u16* __restrict__ zg,
                                                         const float* __restrict__ bias, float* __restrict__ out) {
    __shared__ __align__(16) short lds[32768];          // 64KB: 2 bufs x (A 8192 | B 8192) shorts
    const int t = threadIdx.x, lane = t & 63, w = t >> 6;
    const int wm = w >> 1, wn = w & 1;
    const int l32 = lane & 31, lh = lane >> 5;
    const int m0 = blockIdx.x * 128, n0 = blockIdx.y * 128;

    const int rl8 = lane >> 3;
    const int g = (lane & 7) ^ rl8;                     // logical chunk: 0-3 hi, 4-7 lo
    const u16* selA = (g < 4 ? Ih : Il) + ((g & 3) << 3);
    const u16* selB = (g < 4 ? Wh : Wl) + ((g & 3) << 3);

    int ay[4], ax[4], ab[4], wb[4];
#pragma unroll
    for (int j = 0; j < 4; ++j) {
        const int r = w * 32 + j * 8 + rl8;
        const int gm = m0 + r;
        const int b = gm / 196, rem = gm % 196;
        ay[j] = rem / 14; ax[j] = rem % 14; ab[j] = b * 196;
        wb[j] = (n0 + r) << 8;
    }
    int aoff[4]; bool av[4];
    auto dectap = [&](int kk) {
        const int ky = kk >> 2, kx = kk & 3;
#pragma unroll
        for (int j = 0; j < 4; ++j) {
            const int iy = ay[j] + ky - 1, ix = ax[j] + kx - 1;
            av[j] = ((unsigned)iy < 14u) && ((unsigned)ix < 14u);
            aoff[j] = (ab[j] + iy * 14 + ix) << 8;
        }
    };
    // read offsets (shorts): A row = wm*64+mi*32+l32, hi chunk c = ks*2+lh, lo = ^32
    int offA[2][2], offB[2][2];
#pragma unroll
    for (int mi = 0; mi < 2; ++mi) {
        const int row = wm * 64 + mi * 32 + l32;
#pragma unroll
        for (int ks = 0; ks < 2; ++ks) {
            const int c = ks * 2 + lh;
            offA[mi][ks] = (row << 6) + ((c ^ (row & 7)) << 3);
        }
    }
#pragma unroll
    for (int ni = 0; ni < 2; ++ni) {
        const int row = wn * 64 + ni * 32 + l32;
#pragma unroll
        for (int ks = 0; ks < 2; ++ks) {
            const int c = ks * 2 + lh;
            offB[ni][ks] = 8192 + (row << 6) + ((c ^ (row & 7)) << 3);
        }
    }
    auto stage = [&](int h) {
        const int kk = h >> 3, kc = (h & 7) << 5;
        const int buf = (h & 1) << 14;
#pragma unroll
        for (int j = 0; j < 4; ++j) {
            const int rowb = buf + ((w * 32 + j * 8) << 6);
            const u16* asrc = av[j] ? (selA + aoff[j] + kc) : zg;
            gl_lds16(asrc, lds + rowb);
            gl_lds16(selB + (kk << 16) + wb[j] + kc, lds + 8192 + rowb);
        }
    };

    f32x16 acc[2][2] = {};
    dectap(0);
    stage(0);
    for (int h = 0; h < 128; ++h) {
        const int hn = (h < 127) ? h + 1 : 127;         // last iter: benign re-stage keeps vmcnt accounting
        if ((hn & 7) == 0 && hn == h + 1) dectap(hn >> 3);
        stage(hn);
        PIPE_WAIT8();
        BAR();
        const int base = (h & 1) << 14;
#pragma unroll
        for (int ks = 0; ks < 2; ++ks) {
            short8 bh[2], bl[2];
#pragma unroll
            for (int ni = 0; ni < 2; ++ni) {
                bh[ni] = *(const short8*)&lds[base + offB[ni][ks]];
                bl[ni] = *(const short8*)&lds[base + (offB[ni][ks] ^ 32)];
            }
#pragma unroll
            for (int mi = 0; mi < 2; ++mi) {
                const short8 ah = *(const short8*)&lds[base + offA[mi][ks]];
                const short8 al = *(const short8*)&lds[base + (offA[mi][ks] ^ 32)];
#pragma unroll
                for (int ni = 0; ni < 2; ++ni) {
                    acc[mi][ni] = __builtin_amdgcn_mfma_f32_32x32x16_bf16(ah, bh[ni], acc[mi][ni], 0, 0, 0);
                    acc[mi][ni] = __builtin_amdgcn_mfma_f32_32x32x16_bf16(ah, bl[ni], acc[mi][ni], 0, 0, 0);
                    acc[mi][ni] = __builtin_amdgcn_mfma_f32_32x32x16_bf16(al, bh[ni], acc[mi][ni], 0, 0, 0);
                }
            }
        }
        BAR();
    }
    PIPE_WAIT0();
    // C/D: n = lane&31 (col), m = (reg&3) + 8*(reg>>2) + 4*(lane>>5)
#pragma unroll
    for (int ni = 0; ni < 2; ++ni) {
        const int n = n0 + wn * 64 + ni * 32 + l32;
        const float bv = bias[n];
#pragma unroll
        for (int mi = 0; mi < 2; ++mi) {
            const int mb = m0 + wm * 64 + mi * 32 + 4 * lh;
#pragma unroll
            for (int reg = 0; reg < 16; ++reg) {
                const int m = mb + (reg & 3) + 8 * (reg >> 2);
                out[(size_t)m * 256 + n] = fmaxf(acc[mi][ni][reg] + bv, 0.f);
            }
        }
    }
}

// ---------------- deconv1 parity GEMM v4: 32x32x16 fp16, counted-vmcnt 2-buffer ----------------
// M=25088, N=256, K=ntaps(p)x256. Grid (196, 2, 4).
__global__ __launch_bounds__(256, 2) void deconv1_par_v4(const _Float16* __restrict__ I,
                                                         const _Float16* __restrict__ WC,
                                                         const _Float16* __restrict__ zg,
                                                         const float* __restrict__ bias,
                                                         _Float16* __restrict__ out) {
    __shared__ __align__(16) _Float16 lds[32768];       // 64KB: 2 bufs x (A 8192 | B 8192) halfs
    const int t = threadIdx.x, lane = t & 63, w = t >> 6;
    const int wm = w >> 1, wn = w & 1;
    const int l32 = lane & 31, lh = lane >> 5;
    const int m0 = blockIdx.x * 128, n0 = blockIdx.y * 128;
    const int p = blockIdx.z, dy = p >> 1, dx = p & 1;
    const int nx = 3 - dx;
    const int ntaps = (3 - dy) * nx;
    const int pbase = (dy == 0) ? (dx == 0 ? 0 : 9) : (dx == 0 ? 15 : 21);
    const int nkt = ntaps * 4;

    const int rl8 = lane >> 3;
    const int g = (lane & 7) ^ rl8;
    const _Float16* selA = I + (g << 3);
    const _Float16* selB = WC + ((size_t)pbase << 16) + (g << 3);

    int aY[4], aX[4], ab[4], wb[4];
#pragma unroll
    for (int j = 0; j < 4; ++j) {
        const int r = w * 32 + j * 8 + rl8;
        const int gm = m0 + r;
        const int b = gm / 49, rem = gm % 49;
        aY[j] = rem / 7; aX[j] = rem % 7; ab[j] = b * 49;
        wb[j] = (n0 + r) << 8;
    }
    int aoff[4]; bool av[4];
    auto dectap = [&](int kk) {
        const int oy = kk / nx - (dy == 0 ? 1 : 0);
        const int ox = kk % nx - (dx == 0 ? 1 : 0);
#pragma unroll
        for (int j = 0; j < 4; ++j) {
            const int iy = aY[j] + oy, ix = aX[j] + ox;
            av[j] = ((unsigned)iy < 7u) && ((unsigned)ix < 7u);
            aoff[j] = (ab[j] + iy * 7 + ix) << 8;
        }
    };
    int offA[2][4], offB[2][4];
#pragma unroll
    for (int mi = 0; mi < 2; ++mi) {
        const int row = wm * 64 + mi * 32 + l32;
#pragma unroll
        for (int ks = 0; ks < 4; ++ks) {
            const int c = ks * 2 + lh;
            offA[mi][ks] = (row << 6) + ((c ^ (row & 7)) << 3);
        }
    }
#pragma unroll
    for (int ni = 0; ni < 2; ++ni) {
        const int row = wn * 64 + ni * 32 + l32;
#pragma unroll
        for (int ks = 0; ks < 4; ++ks) {
            const int c = ks * 2 + lh;
            offB[ni][ks] = 8192 + (row << 6) + ((c ^ (row & 7)) << 3);
        }
    }
    auto stage = [&](int kt) {
        const int kk = kt >> 2, kc = (kt & 3) << 6;
        const int buf = (kt & 1) << 14;
#pragma unroll
        for (int j = 0; j < 4; ++j) {
            const int rowb = buf + ((w * 32 + j * 8) << 6);
            const _Float16* asrc = av[j] ? (selA + aoff[j] + kc) : zg;
            gl_lds16(asrc, lds + rowb);
            gl_lds16(selB + (kk << 16) + wb[j] + kc, lds + 8192 + rowb);
        }
    };

    f32x16 acc[2][2] = {};
    dectap(0);
    stage(0);
    for (int kt = 0; kt < nkt; ++kt) {
        const int ktn = (kt < nkt - 1) ? kt + 1 : kt;
        if ((ktn & 3) == 0 && ktn == kt + 1) dectap(ktn >> 2);
        stage(ktn);
        PIPE_WAIT8();
        BAR();
        const int base = (kt & 1) << 14;
#pragma unroll
        for (int ks = 0; ks < 4; ++ks) {
            half8 b8[2];
#pragma unroll
            for (int ni = 0; ni < 2; ++ni)
                b8[ni] = *(const half8*)&lds[base + offB[ni][ks]];
#pragma unroll
            for (int mi = 0; mi < 2; ++mi) {
                const half8 a8 = *(const half8*)&lds[base + offA[mi][ks]];
#pragma unroll
                for (int ni = 0; ni < 2; ++ni)
                    acc[mi][ni] = __builtin_amdgcn_mfma_f32_32x32x16_f16(a8, b8[ni], acc[mi][ni], 0, 0, 0);
            }
        }
        BAR();
    }
    PIPE_WAIT0();
#pragma unroll
    for (int mi = 0; mi < 2; ++mi) {
        const int mb = m0 + wm * 64 + mi * 32 + 4 * lh;
#pragma unroll
        for (int reg = 0; reg < 16; ++reg) {
            const int m = mb + (reg & 3) + 8 * (reg >> 2);
            const int b = m / 49, rem = m % 49;
            const int Y = rem / 7, X = rem % 7;
            _Float16* op = out + (((size_t)(b * 196 + (2 * Y + dy) * 14 + (2 * X + dx))) << 8);
#pragma unroll
            for (int ni = 0; ni < 2; ++ni) {
                const int col = n0 + wn * 64 + ni * 32 + l32;
                op[col] = (_Float16)fmaxf(acc[mi][ni][reg] + bias[col], 0.f);
            }
        }
    }
}

// ---------------- maxpool 2x2 on h2 (f32) -> h2p ----------------
__global__ __launch_bounds__(256) void pool2_kernel(const float* __restrict__ h2, float* __restrict__ h2p) {
    int idx = blockIdx.x * 256 + threadIdx.x;           // 256*49*256
    int c = idx & 255;
    int rest = idx >> 8;
    int px = rest % 7, py = (rest / 7) % 7, b = rest / 49;
    const float* base = h2 + (((size_t)(b * 14 + 2 * py)) * 14 + 2 * px) * 256 + c;
    float v = fmaxf(fmaxf(base[0], base[256]), fmaxf(base[14 * 256], base[14 * 256 + 256]));
    h2p[idx] = v;
}

// ---------------- encoder split-K stage 1: 98 k-slices of 128, ew read once ----------------
__global__ __launch_bounds__(256) void encp_kernel(const float* __restrict__ h2p, const float* __restrict__ ew,
                                                   float* __restrict__ partials) {
    __shared__ float ews[8192];                         // [128 k][64 n]
    __shared__ float hbuf[8][128];
    const int t = threadIdx.x, c = blockIdx.x;
    const float* esrc = ew + (size_t)c * 8192;
    for (int i = t; i < 2048; i += 256)
        *(f32x4*)&ews[i * 4] = *(const f32x4*)&esrc[i * 4];
    const int n = t & 63, sub = t >> 6;
    const int rr = t >> 5, kq = (t & 31) << 2;
    float* pout = partials + (size_t)c * 16384;
    for (int bi = 0; bi < 32; ++bi) {
        __syncthreads();
        *(f32x4*)&hbuf[rr][kq] = *(const f32x4*)&h2p[(size_t)(bi * 8 + rr) * 12544 + c * 128 + kq];
        __syncthreads();
        float a0 = 0.f, a1 = 0.f;
        for (int k = 0; k < 128; ++k) {
            const float wv = ews[k * 64 + n];
            a0 += hbuf[sub][k] * wv;
            a1 += hbuf[sub + 4][k] * wv;
        }
        pout[(bi * 8 + sub) * 64 + n] = a0;
        pout[(bi * 8 + sub + 4) * 64 + n] = a1;
    }
}

// ---------------- encoder stage 2: reduce 98 partials + bias -> zcat rows 0..255 ----------------
__global__ __launch_bounds__(256) void encr_kernel(const float* __restrict__ partials, const float* __restrict__ eb,
                                                   float* __restrict__ zcat) {
    const int o = blockIdx.x * 256 + threadIdx.x;       // 16384
    float s = eb[o & 63];
    for (int c = 0; c < 98; ++c) s += partials[(size_t)c * 16384 + o];
    zcat[o] = s;
}

// ---------------- SOM argmin ----------------
__global__ __launch_bounds__(256) void som_kernel(const float* __restrict__ emb, float* __restrict__ zcat) {
    __shared__ float zrow[64];
    __shared__ float sd[256];
    __shared__ int si[256];
    const int b = blockIdx.x, t = threadIdx.x;
    if (t < 64) zrow[t] = zcat[b * 64 + t];
    __syncthreads();
    float acc = 0.f;
    const float* e = emb + t * 64;
    for (int d = 0; d < 64; ++d) { float df = zrow[d] - e[d]; acc += df * df; }
    sd[t] = acc; si[t] = t;
    __syncthreads();
    for (int off = 128; off >= 1; off >>= 1) {
        if (t < off) {
            float d2 = sd[t + off]; int i2 = si[t + off];
            if (d2 < sd[t] || (d2 == sd[t] && i2 < si[t])) { sd[t] = d2; si[t] = i2; }
        }
        __syncthreads();
    }
    const int k = si[0];
    if (t < 64) zcat[(256 + b) * 64 + t] = emb[k * 64 + t];
}

// ---------------- decoder linear ----------------
__global__ __launch_bounds__(256) void dec_kernel(const float* __restrict__ zcat, const float* __restrict__ dw,
                                                  const float* __restrict__ db, _Float16* __restrict__ dech) {
    __shared__ float z[8][64];
    const int t = threadIdx.x;
    const int bg = blockIdx.x / 49;
    const int nc = blockIdx.x % 49;
    for (int i = t; i < 512; i += 256) z[i >> 6][i & 63] = zcat[bg * 512 + i];
    __syncthreads();
    const int n = nc * 256 + t;
    const float bv = db[n];
    float acc[8];
#pragma unroll
    for (int j = 0; j < 8; ++j) acc[j] = bv;
    for (int k = 0; k < 64; ++k) {
        float wv = dw[(size_t)k * 12544 + n];
#pragma unroll
        for (int j = 0; j < 8; ++j) acc[j] += z[j][k] * wv;
    }
#pragma unroll
    for (int j = 0; j < 8; ++j) dech[((size_t)(bg * 8 + j)) * 12544 + n] = (_Float16)acc[j];
}

// ---------------- deconv2 v5: quarter-image blocks (6-row LDS stage), parity 9-tap, sigmoid ----------------
// Block = (b, q), q in 0..3 -> output rows oy = 7q..7q+6. Staged d1 rows r0..r0+5, r0 = min(3q, 8).
// Verified needed iy per q: q0: 0..4, q1: 3..7, q2: 6..11, q3: 10..13 — all inside [r0, r0+6) ⊂ [0,13].
__global__ __launch_bounds__(256) void deconv2_v5(const _Float16* __restrict__ d1, const _Float16* __restrict__ w2c,
                                                  const float* __restrict__ bias, float* __restrict__ out) {
    __shared__ _Float16 ds[6 * 14 * 256];               // 42KB
    const int t = threadIdx.x;
    const int blk = blockIdx.x;                         // 512 b x 4 quarters
    const int q = blk & 3, b = blk >> 2;
    const int r0 = (q == 3) ? 8 : 3 * q;
    for (int i = t; i < 2688; i += 256) {               // 6 rows x 448 half8 units
        const int r = i / 448, rem = i % 448;
        *(half8*)&ds[r * 3584 + rem * 8] =
            *(const half8*)&d1[((size_t)(b * 14 + r0 + r) * 14) * 256 + rem * 8];
    }
    const int lane = t & 63, wv = t >> 6;
    const int ch0 = lane * 4;
    half4 wreg[4][9];
#pragma unroll
    for (int p = 0; p < 4; ++p)
#pragma unroll
        for (int j = 0; j < 9; ++j)
            wreg[p][j] = *(const half4*)&w2c[(p * 9 + j) * 256 + ch0];
    const float bv = bias[0];
    __syncthreads();
    for (int pi = 0; pi < 49; ++pi) {
        const int ql = pi * 4 + wv;                     // 196 px per quarter
        const int oy = 7 * q + ql / 28, ox = ql % 28;
        const int dy = oy & 1, Y = oy >> 1;
        const int dxp = ox & 1, X = ox >> 1;
        const half4* wp = wreg[dy * 2 + dxp];
        float acc = 0.f;
#pragma unroll
        for (int j = 0; j < 9; ++j) {
            const int iy = Y + (j / 3) - (dy ? 0 : 1);
            const int ix = X + (j % 3) - (dxp ? 0 : 1);
            if (iy >= r0 && iy < r0 + 6 && (unsigned)ix < 14u) {
                const half4 dv = *(const half4*)&ds[((iy - r0) * 14 + ix) * 256 + ch0];
                const half4 w4 = wp[j];
                half2v dlo = {dv.x, dv.y}, dhi = {dv.z, dv.w};
                half2v wlo = {w4.x, w4.y}, whi = {w4.z, w4.w};
                acc = __builtin_amdgcn_fdot2(dlo, wlo, acc, false);
                acc = __builtin_amdgcn_fdot2(dhi, whi, acc, false);
            }
        }
#pragma unroll
        for (int off = 32; off; off >>= 1) acc += __shfl_xor(acc, off);
        if (lane == 0) out[(size_t)b * 784 + oy * 28 + ox] = 1.f / (1.f + expf(-(acc + bv)));
    }
}

extern "C" void kernel_launch(void* const* d_in, const int* in_sizes, int n_in,
                              void* d_out, int out_size, void* d_ws, size_t ws_size,
                              hipStream_t stream) {
    const float* x    = (const float*)d_in[0];
    const float* c1w  = (const float*)d_in[1];
    const float* c1b  = (const float*)d_in[2];
    const float* c2w  = (const float*)d_in[3];
    const float* c2b  = (const float*)d_in[4];
    const float* ew   = (const float*)d_in[5];
    const float* eb   = (const float*)d_in[6];
    const float* emb  = (const float*)d_in[7];
    const float* dw   = (const float*)d_in[8];
    const float* db   = (const float*)d_in[9];
    const float* dc1w = (const float*)d_in[10];
    const float* dc1b = (const float*)d_in[11];
    const float* dc2w = (const float*)d_in[12];
    const float* dc2b = (const float*)d_in[13];
    float* out = (float*)d_out;

    char* ws = (char*)d_ws;
    size_t off = 0;
    auto alloc = [&](size_t bytes) { size_t o = off; off += (bytes + 255) & ~(size_t)255; return o; };

    u16*      h1p_hi = (u16*)(ws + alloc((size_t)256 * 196 * 256 * 2));
    u16*      h1p_lo = (u16*)(ws + alloc((size_t)256 * 196 * 256 * 2));
    u16*      w2T_hi = (u16*)(ws + alloc((size_t)16 * 256 * 256 * 2));
    u16*      w2T_lo = (u16*)(ws + alloc((size_t)16 * 256 * 256 * 2));
    float*    h2     = (float*)(ws + alloc((size_t)256 * 196 * 256 * 4));
    float*    h2p    = (float*)(ws + alloc((size_t)256 * 49 * 256 * 4));
    float*    zcat   = (float*)(ws + alloc((size_t)512 * 64 * 4));
    _Float16* dech   = (_Float16*)(ws + alloc((size_t)512 * 49 * 256 * 2));
    _Float16* wc1    = (_Float16*)(ws + alloc((size_t)25 * 256 * 256 * 2));
    _Float16* d1     = (_Float16*)(ws + alloc((size_t)512 * 196 * 256 * 2));
    _Float16* w2c    = (_Float16*)(ws + alloc((size_t)9216 * 2));
    u16*      zg     = (u16*)(ws + alloc(256));
    float*    partials = h2;                            // h2 is dead after pool2; 6.4MB << 51MB

    hipMemsetAsync(zg, 0, 256, stream);
    wprep_split_kernel<<<4096, 256, 0, stream>>>(c2w, w2T_hi, w2T_lo);
    wprep_dc1_par<<<6400, 256, 0, stream>>>(dc1w, wc1);
    wprep_dc2_par<<<36, 256, 0, stream>>>(dc2w, w2c);
    conv1_pool_v2<<<3584, 256, 0, stream>>>(x, c1w, c1b, h1p_hi, h1p_lo);
    conv2_split_v4<<<dim3(392, 2), 256, 0, stream>>>(h1p_hi, h1p_lo, w2T_hi, w2T_lo, zg, c2b, h2);
    pool2_kernel<<<12544, 256, 0, stream>>>(h2, h2p);
    encp_kernel<<<98, 256, 0, stream>>>(h2p, ew, partials);
    encr_kernel<<<64, 256, 0, stream>>>(partials, eb, zcat);
    som_kernel<<<256, 256, 0, stream>>>(emb, zcat);
    dec_kernel<<<3136, 256, 0, stream>>>(zcat, dw, db, dech);
    deconv1_par_v4<<<dim3(196, 2, 4), 256, 0, stream>>>(dech, wc1, (const _Float16*)zg, dc1b, d1);
    deconv2_v5<<<2048, 256, 0, stream>>>(d1, w2c, dc2b, out);
}

// Round 6
// 999.802 us; speedup vs baseline: 1.0838x; 1.0838x over previous
//
#include <hip/hip_runtime.h>
#include <hip/hip_bf16.h>

typedef unsigned short u16;
using short8 = __attribute__((ext_vector_type(8))) short;
using half8  = __attribute__((ext_vector_type(8))) _Float16;
using half4  = __attribute__((ext_vector_type(4))) _Float16;
using half2v = __attribute__((ext_vector_type(2))) _Float16;
using f32x4  = __attribute__((ext_vector_type(4))) float;

__device__ __forceinline__ u16 f2bf(float f) {
    unsigned int u = __float_as_uint(f);
    u += 0x7FFFu + ((u >> 16) & 1u);   // RNE
    return (u16)(u >> 16);
}
__device__ __forceinline__ float bf2f(u16 h) {
    return __uint_as_float(((unsigned int)h) << 16);
}

__device__ __forceinline__ void gl_lds16(const void* g, void* l) {
    __builtin_amdgcn_global_load_lds((const __attribute__((address_space(1))) void*)g,
                                     (__attribute__((address_space(3))) void*)l, 16, 0, 0);
}

#define PIPE_WAIT8() asm volatile("s_waitcnt vmcnt(8)" ::: "memory")
#define PIPE_WAIT0() asm volatile("s_waitcnt vmcnt(0)" ::: "memory")
#define BAR() __builtin_amdgcn_s_barrier()

// ---------------- weight prep: conv2 HWIO -> [kk][n][ci], split bf16 hi/lo ----------------
__global__ __launch_bounds__(256) void wprep_split_kernel(const float* __restrict__ src,
                                                          u16* __restrict__ hi, u16* __restrict__ lo) {
    int idx = blockIdx.x * 256 + threadIdx.x;          // 16*256*256
    int ci = idx & 255, n = (idx >> 8) & 255, kk = idx >> 16;
    float v = src[(kk * 256 + ci) * 256 + n];
    u16 h = f2bf(v);
    hi[idx] = h;
    lo[idx] = f2bf(v - bf2f(h));
}

// ---------------- weight prep: deconv1 parity-combined -> [tap_g][n][ci] fp16 (25 taps) ----------------
__global__ __launch_bounds__(256) void wprep_dc1_par(const float* __restrict__ src, _Float16* __restrict__ dst) {
    const int idx = blockIdx.x * 256 + threadIdx.x;    // 25*65536
    const int ci = idx & 255, n = (idx >> 8) & 255, tg = idx >> 16;
    int p, j;
    if (tg < 9)       { p = 0; j = tg; }
    else if (tg < 15) { p = 1; j = tg - 9; }
    else if (tg < 21) { p = 2; j = tg - 15; }
    else              { p = 3; j = tg - 21; }
    const int dy = p >> 1, dx = p & 1;
    const int nx = 3 - dx;
    const int oyi = j / nx, oxi = j % nx;
    int ky0, kyn, kx0, kxn;
    if (dy == 0) { ky0 = (oyi == 0) ? 0 : (oyi == 1 ? 1 : 3); kyn = (oyi == 1) ? 2 : 1; }
    else         { ky0 = (oyi == 0) ? 0 : 2;                  kyn = 2; }
    if (dx == 0) { kx0 = (oxi == 0) ? 0 : (oxi == 1 ? 1 : 3); kxn = (oxi == 1) ? 2 : 1; }
    else         { kx0 = (oxi == 0) ? 0 : 2;                  kxn = 2; }
    float s = 0.f;
    for (int a = 0; a < kyn; ++a)
        for (int c = 0; c < kxn; ++c)
            s += src[(((ky0 + a) * 4 + (kx0 + c)) * 256 + ci) * 256 + n];
    dst[((size_t)tg << 16) + (n << 8) + ci] = (_Float16)s;
}

// ---------------- weight prep: deconv2 parity-combined -> [p][9][256] fp16 (zero-padded taps) ----------------
__global__ __launch_bounds__(256) void wprep_dc2_par(const float* __restrict__ src, _Float16* __restrict__ dst) {
    const int idx = blockIdx.x * 256 + threadIdx.x;    // 36*256 = 9216
    if (idx >= 9216) return;
    const int ci = idx & 255;
    const int j9 = (idx >> 8) % 9, p = (idx >> 8) / 9;
    const int dy = p >> 1, dx = p & 1;
    const int oyi = j9 / 3, oxi = j9 % 3;
    float s = 0.f;
    if (!((dy == 1 && oyi == 2) || (dx == 1 && oxi == 2))) {
        int ky0, kyn, kx0, kxn;
        if (dy == 0) { ky0 = (oyi == 0) ? 0 : (oyi == 1 ? 1 : 3); kyn = (oyi == 1) ? 2 : 1; }
        else         { ky0 = (oyi == 0) ? 0 : 2;                  kyn = 2; }
        if (dx == 0) { kx0 = (oxi == 0) ? 0 : (oxi == 1 ? 1 : 3); kxn = (oxi == 1) ? 2 : 1; }
        else         { kx0 = (oxi == 0) ? 0 : 2;                  kxn = 2; }
        for (int a = 0; a < kyn; ++a)
            for (int c = 0; c < kxn; ++c)
                s += src[((ky0 + a) * 4 + (kx0 + c)) * 256 + ci];
    }
    dst[idx] = (_Float16)s;
}

// ---------------- conv1 (1->256) + ReLU + maxpool, block = (b, pooled row) ----------------
__global__ __launch_bounds__(256) void conv1_pool_v2(const float* __restrict__ x,
                                                     const float* __restrict__ w,
                                                     const float* __restrict__ bias,
                                                     u16* __restrict__ hi, u16* __restrict__ lo) {
    __shared__ float xs[5][32];
    const int blk = blockIdx.x;                         // b*14 + py
    const int py = blk % 14, b = blk / 14;
    const int t = threadIdx.x;
    for (int i = t; i < 160; i += 256) {
        const int r = i >> 5, c = i & 31;
        const int gy = 2 * py - 1 + r, gx = c - 1;
        float v = 0.f;
        if ((unsigned)gy < 28u && (unsigned)gx < 28u) v = x[(b * 28 + gy) * 28 + gx];
        xs[r][c] = v;
    }
    __syncthreads();
    float wr[16];
#pragma unroll
    for (int k = 0; k < 16; ++k) wr[k] = w[k * 256 + t];
    const float bs = bias[t];
    for (int px = 0; px < 14; ++px) {
        float m = 0.f;
#pragma unroll
        for (int dy = 0; dy < 2; ++dy)
#pragma unroll
            for (int dx = 0; dx < 2; ++dx) {
                float a = bs;
#pragma unroll
                for (int ky = 0; ky < 4; ++ky)
#pragma unroll
                    for (int kx = 0; kx < 4; ++kx)
                        a += xs[dy + ky][2 * px + dx + kx] * wr[ky * 4 + kx];
                m = fmaxf(m, a);
            }
        u16 h = f2bf(m);
        const int o = ((b * 14 + py) * 14 + px) * 256 + t;
        hi[o] = h;
        lo[o] = f2bf(m - bf2f(h));
    }
}

// ---------------- conv2 v2 (best known): 128x128 tile, global_load_lds + XOR-swizzle, split-bf16 3-pass ----------------
// M = 50176, N = 256, K = 16 x 256.  Grid (392, 2), 256 threads (4 waves, each owns 64x64).
__global__ __launch_bounds__(256, 2) void conv2_split_v2(const u16* __restrict__ Ih, const u16* __restrict__ Il,
                                                         const u16* __restrict__ Wh, const u16* __restrict__ Wl,
                                                         const u16* __restrict__ zg,
                                                         const float* __restrict__ bias, float* __restrict__ out) {
    __shared__ __align__(16) short lds[32768];          // AH 0, AL 8192, BH 16384, BL 24576 (64 KiB)
    const int AL = 8192, BH = 16384, BL = 24576;
    const int t = threadIdx.x, lane = t & 63, w = t >> 6;
    const int wm = w >> 1, wn = w & 1;
    const int l16 = lane & 15, l4 = lane >> 4;
    const int m0 = blockIdx.x * 128, n0 = blockIdx.y * 128;
    // staging geometry: wave w stages rows 32w..32w+31 of each array; instr j covers 8 rows.
    const int rl = lane >> 3;                           // row within 8-group (== row&7)
    const int chS = (((lane & 7) ^ rl)) << 3;           // source chunk offset in shorts (16B units)
    int ay[4], ax[4], ab[4], wb[4], aoff[4];
    bool av[4];
#pragma unroll
    for (int j = 0; j < 4; ++j) {
        const int r = w * 32 + j * 8 + rl;
        const int gm = m0 + r;
        const int b = gm / 196, rem = gm % 196;
        ay[j] = rem / 14; ax[j] = rem % 14; ab[j] = b * 196;
        wb[j] = (n0 + r) << 8;
    }
    f32x4 acc[4][4] = {};

    for (int kt = 0; kt < 64; ++kt) {
        const int kk = kt >> 2;
        if ((kt & 3) == 0) {
            const int ky = kk >> 2, kx = kk & 3;
#pragma unroll
            for (int j = 0; j < 4; ++j) {
                const int iy = ay[j] + ky - 1, ix = ax[j] + kx - 1;
                av[j] = ((unsigned)iy < 14u) && ((unsigned)ix < 14u);
                aoff[j] = (ab[j] + iy * 14 + ix) << 8;
            }
        }
        const int kc = (kt & 3) << 6;
        __syncthreads();
#pragma unroll
        for (int j = 0; j < 4; ++j) {
            const int rowb = (w * 32 + j * 8) << 6;     // row*64 shorts
            const u16* gh = av[j] ? (Ih + aoff[j] + kc + chS) : zg;
            const u16* gl = av[j] ? (Il + aoff[j] + kc + chS) : zg;
            gl_lds16(gh, lds + rowb);
            gl_lds16(gl, lds + AL + rowb);
            const int woff = (kk << 16) + wb[j] + kc + chS;
            gl_lds16(Wh + woff, lds + BH + rowb);
            gl_lds16(Wl + woff, lds + BL + rowb);
        }
        __syncthreads();
#pragma unroll
        for (int ks = 0; ks < 2; ++ks) {
            short8 bhf[4], blf[4];
#pragma unroll
            for (int ni = 0; ni < 4; ++ni) {
                const int row = wn * 64 + ni * 16 + l16;
                const int p = (ks * 4 + l4) ^ (row & 7);
                const int off = (row << 6) + (p << 3);
                bhf[ni] = *(const short8*)&lds[BH + off];
                blf[ni] = *(const short8*)&lds[BL + off];
            }
#pragma unroll
            for (int mi = 0; mi < 4; ++mi) {
                const int row = wm * 64 + mi * 16 + l16;
                const int p = (ks * 4 + l4) ^ (row & 7);
                const int off = (row << 6) + (p << 3);
                const short8 ah = *(const short8*)&lds[off];
                const short8 al = *(const short8*)&lds[AL + off];
#pragma unroll
                for (int ni = 0; ni < 4; ++ni) {
                    acc[mi][ni] = __builtin_amdgcn_mfma_f32_16x16x32_bf16(ah, bhf[ni], acc[mi][ni], 0, 0, 0);
                    acc[mi][ni] = __builtin_amdgcn_mfma_f32_16x16x32_bf16(ah, blf[ni], acc[mi][ni], 0, 0, 0);
                    acc[mi][ni] = __builtin_amdgcn_mfma_f32_16x16x32_bf16(al, bhf[ni], acc[mi][ni], 0, 0, 0);
                }
            }
        }
    }
#pragma unroll
    for (int ni = 0; ni < 4; ++ni) {
        const int col = n0 + wn * 64 + ni * 16 + l16;
        const float bv = bias[col];
#pragma unroll
        for (int mi = 0; mi < 4; ++mi) {
            const int mrow = m0 + wm * 64 + mi * 16 + l4 * 4;
#pragma unroll
            for (int r = 0; r < 4; ++r)
                out[(size_t)(mrow + r) * 256 + col] = fmaxf(acc[mi][ni][r] + bv, 0.f);
        }
    }
}

// ---------------- deconv1 parity GEMM (round-3 best known): 16x16x32 fp16, counted-vmcnt 2-buffer ----------------
// M=25088, N=256, K=ntaps(p)x256. Grid (196, 2, 4). Output to upsampled 14x14 grid (2Y+dy, 2X+dx).
__global__ __launch_bounds__(256, 2) void deconv1_par(const _Float16* __restrict__ I,
                                                      const _Float16* __restrict__ WC,
                                                      const _Float16* __restrict__ zg,
                                                      const float* __restrict__ bias,
                                                      _Float16* __restrict__ out) {
    __shared__ __align__(16) _Float16 lds[32768];       // 64KB: 2 bufs x (A 8192 | B 8192) halfs
    const int t = threadIdx.x, lane = t & 63, w = t >> 6;
    const int wm = w >> 1, wn = w & 1;
    const int l16 = lane & 15, l4 = lane >> 4;
    const int m0 = blockIdx.x * 128, n0 = blockIdx.y * 128;
    const int p = blockIdx.z, dy = p >> 1, dx = p & 1;
    const int nx = 3 - dx;
    const int ntaps = (3 - dy) * nx;
    const int pbase = (dy == 0) ? (dx == 0 ? 0 : 9) : (dx == 0 ? 15 : 21);
    const int nkt = ntaps * 4;

    const int rl8 = lane >> 3;
    const int g = (lane & 7) ^ rl8;
    const _Float16* selA = I + (g << 3);
    const _Float16* selB = WC + ((size_t)pbase << 16) + (g << 3);

    int aY[4], aX[4], ab[4], wb[4];
#pragma unroll
    for (int j = 0; j < 4; ++j) {
        const int r = w * 32 + j * 8 + rl8;
        const int gm = m0 + r;
        const int b = gm / 49, rem = gm % 49;
        aY[j] = rem / 7; aX[j] = rem % 7; ab[j] = b * 49;
        wb[j] = (n0 + r) << 8;
    }
    int aoff[4]; bool av[4];
    auto dectap = [&](int kk) {
        const int oy = kk / nx - (dy == 0 ? 1 : 0);
        const int ox = kk % nx - (dx == 0 ? 1 : 0);
#pragma unroll
        for (int j = 0; j < 4; ++j) {
            const int iy = aY[j] + oy, ix = aX[j] + ox;
            av[j] = ((unsigned)iy < 7u) && ((unsigned)ix < 7u);
            aoff[j] = (ab[j] + iy * 7 + ix) << 8;
        }
    };
    int rdA[4], rdB[4];
#pragma unroll
    for (int mi = 0; mi < 4; ++mi) {
        const int ra = wm * 64 + mi * 16 + l16;
        rdA[mi] = (ra << 6) + ((l4 ^ (ra & 7)) << 3);
    }
#pragma unroll
    for (int ni = 0; ni < 4; ++ni) {
        const int rb = wn * 64 + ni * 16 + l16;
        rdB[ni] = 8192 + (rb << 6) + ((l4 ^ (rb & 7)) << 3);
    }
    auto stage = [&](int kt) {
        const int kk = kt >> 2, kc = (kt & 3) << 6;
        const int buf = (kt & 1) << 14;
#pragma unroll
        for (int j = 0; j < 4; ++j) {
            const int rowb = buf + ((w * 32 + j * 8) << 6);
            const _Float16* asrc = av[j] ? (selA + aoff[j] + kc) : zg;
            gl_lds16(asrc, lds + rowb);
            gl_lds16(selB + (kk << 16) + wb[j] + kc, lds + 8192 + rowb);
        }
    };

    f32x4 acc[4][4] = {};
    dectap(0);
    stage(0);
    for (int kt = 0; kt < nkt; ++kt) {
        const int ktn = (kt < nkt - 1) ? kt + 1 : kt;
        if ((ktn & 3) == 0 && ktn == kt + 1) dectap(ktn >> 2);
        stage(ktn);
        PIPE_WAIT8();
        BAR();
        const int base = (kt & 1) << 14;
#pragma unroll
        for (int ks = 0; ks < 2; ++ks) {
            const int x32 = ks << 5;
            half8 b8[4];
#pragma unroll
            for (int ni = 0; ni < 4; ++ni)
                b8[ni] = *(const half8*)&lds[base + (rdB[ni] ^ x32)];
#pragma unroll
            for (int mi = 0; mi < 4; ++mi) {
                const half8 a8 = *(const half8*)&lds[base + (rdA[mi] ^ x32)];
#pragma unroll
                for (int ni = 0; ni < 4; ++ni)
                    acc[mi][ni] = __builtin_amdgcn_mfma_f32_16x16x32_f16(a8, b8[ni], acc[mi][ni], 0, 0, 0);
            }
        }
        BAR();
    }
    PIPE_WAIT0();
#pragma unroll
    for (int mi = 0; mi < 4; ++mi) {
        const int mb = m0 + wm * 64 + mi * 16 + l4 * 4;
#pragma unroll
        for (int r = 0; r < 4; ++r) {
            const int m = mb + r;
            const int b = m / 49, rem = m % 49;
            const int Y = rem / 7, X = rem % 7;
            _Float16* op = out + (((size_t)(b * 196 + (2 * Y + dy) * 14 + (2 * X + dx))) << 8);
#pragma unroll
            for (int ni = 0; ni < 4; ++ni) {
                const int col = n0 + wn * 64 + ni * 16 + l16;
                op[col] = (_Float16)fmaxf(acc[mi][ni][r] + bias[col], 0.f);
            }
        }
    }
}

// ---------------- maxpool 2x2 on h2 (f32) -> h2p ----------------
__global__ __launch_bounds__(256) void pool2_kernel(const float* __restrict__ h2, float* __restrict__ h2p) {
    int idx = blockIdx.x * 256 + threadIdx.x;           // 256*49*256
    int c = idx & 255;
    int rest = idx >> 8;
    int px = rest % 7, py = (rest / 7) % 7, b = rest / 49;
    const float* base = h2 + (((size_t)(b * 14 + 2 * py)) * 14 + 2 * px) * 256 + c;
    float v = fmaxf(fmaxf(base[0], base[256]), fmaxf(base[14 * 256], base[14 * 256 + 256]));
    h2p[idx] = v;
}

// ---------------- encoder split-K stage 1: 98 k-slices of 128, ew read once ----------------
__global__ __launch_bounds__(256) void encp_kernel(const float* __restrict__ h2p, const float* __restrict__ ew,
                                                   float* __restrict__ partials) {
    __shared__ float ews[8192];                         // [128 k][64 n]
    __shared__ float hbuf[8][128];
    const int t = threadIdx.x, c = blockIdx.x;
    const float* esrc = ew + (size_t)c * 8192;
    for (int i = t; i < 2048; i += 256)
        *(f32x4*)&ews[i * 4] = *(const f32x4*)&esrc[i * 4];
    const int n = t & 63, sub = t >> 6;
    const int rr = t >> 5, kq = (t & 31) << 2;
    float* pout = partials + (size_t)c * 16384;
    for (int bi = 0; bi < 32; ++bi) {
        __syncthreads();
        *(f32x4*)&hbuf[rr][kq] = *(const f32x4*)&h2p[(size_t)(bi * 8 + rr) * 12544 + c * 128 + kq];
        __syncthreads();
        float a0 = 0.f, a1 = 0.f;
        for (int k = 0; k < 128; ++k) {
            const float wv = ews[k * 64 + n];
            a0 += hbuf[sub][k] * wv;
            a1 += hbuf[sub + 4][k] * wv;
        }
        pout[(bi * 8 + sub) * 64 + n] = a0;
        pout[(bi * 8 + sub + 4) * 64 + n] = a1;
    }
}

// ---------------- encoder stage 2: reduce 98 partials + bias -> zcat rows 0..255 ----------------
__global__ __launch_bounds__(256) void encr_kernel(const float* __restrict__ partials, const float* __restrict__ eb,
                                                   float* __restrict__ zcat) {
    const int o = blockIdx.x * 256 + threadIdx.x;       // 16384
    float s = eb[o & 63];
    for (int c = 0; c < 98; ++c) s += partials[(size_t)c * 16384 + o];
    zcat[o] = s;
}

// ---------------- SOM argmin ----------------
__global__ __launch_bounds__(256) void som_kernel(const float* __restrict__ emb, float* __restrict__ zcat) {
    __shared__ float zrow[64];
    __shared__ float sd[256];
    __shared__ int si[256];
    const int b = blockIdx.x, t = threadIdx.x;
    if (t < 64) zrow[t] = zcat[b * 64 + t];
    __syncthreads();
    float acc = 0.f;
    const float* e = emb + t * 64;
    for (int d = 0; d < 64; ++d) { float df = zrow[d] - e[d]; acc += df * df; }
    sd[t] = acc; si[t] = t;
    __syncthreads();
    for (int off = 128; off >= 1; off >>= 1) {
        if (t < off) {
            float d2 = sd[t + off]; int i2 = si[t + off];
            if (d2 < sd[t] || (d2 == sd[t] && i2 < si[t])) { sd[t] = d2; si[t] = i2; }
        }
        __syncthreads();
    }
    const int k = si[0];
    if (t < 64) zcat[(256 + b) * 64 + t] = emb[k * 64 + t];
}

// ---------------- decoder linear ----------------
__global__ __launch_bounds__(256) void dec_kernel(const float* __restrict__ zcat, const float* __restrict__ dw,
                                                  const float* __restrict__ db, _Float16* __restrict__ dech) {
    __shared__ float z[8][64];
    const int t = threadIdx.x;
    const int bg = blockIdx.x / 49;
    const int nc = blockIdx.x % 49;
    for (int i = t; i < 512; i += 256) z[i >> 6][i & 63] = zcat[bg * 512 + i];
    __syncthreads();
    const int n = nc * 256 + t;
    const float bv = db[n];
    float acc[8];
#pragma unroll
    for (int j = 0; j < 8; ++j) acc[j] = bv;
    for (int k = 0; k < 64; ++k) {
        float wv = dw[(size_t)k * 12544 + n];
#pragma unroll
        for (int j = 0; j < 8; ++j) acc[j] += z[j][k] * wv;
    }
#pragma unroll
    for (int j = 0; j < 8; ++j) dech[((size_t)(bg * 8 + j)) * 12544 + n] = (_Float16)acc[j];
}

// ---------------- deconv2 v5: quarter-image blocks (6-row LDS stage), parity 9-tap, sigmoid ----------------
// Block = (b, q), q in 0..3 -> output rows oy = 7q..7q+6. Staged d1 rows r0..r0+5, r0 = min(3q, 8).
__global__ __launch_bounds__(256) void deconv2_v5(const _Float16* __restrict__ d1, const _Float16* __restrict__ w2c,
                                                  const float* __restrict__ bias, float* __restrict__ out) {
    __shared__ _Float16 ds[6 * 14 * 256];               // 42KB
    const int t = threadIdx.x;
    const int blk = blockIdx.x;                         // 512 b x 4 quarters
    const int q = blk & 3, b = blk >> 2;
    const int r0 = (q == 3) ? 8 : 3 * q;
    for (int i = t; i < 2688; i += 256) {               // 6 rows x 448 half8 units
        const int r = i / 448, rem = i % 448;
        *(half8*)&ds[r * 3584 + rem * 8] =
            *(const half8*)&d1[((size_t)(b * 14 + r0 + r) * 14) * 256 + rem * 8];
    }
    const int lane = t & 63, wv = t >> 6;
    const int ch0 = lane * 4;
    half4 wreg[4][9];
#pragma unroll
    for (int p = 0; p < 4; ++p)
#pragma unroll
        for (int j = 0; j < 9; ++j)
            wreg[p][j] = *(const half4*)&w2c[(p * 9 + j) * 256 + ch0];
    const float bv = bias[0];
    __syncthreads();
    for (int pi = 0; pi < 49; ++pi) {
        const int ql = pi * 4 + wv;                     // 196 px per quarter
        const int oy = 7 * q + ql / 28, ox = ql % 28;
        const int dy = oy & 1, Y = oy >> 1;
        const int dxp = ox & 1, X = ox >> 1;
        const half4* wp = wreg[dy * 2 + dxp];
        float acc = 0.f;
#pragma unroll
        for (int j = 0; j < 9; ++j) {
            const int iy = Y + (j / 3) - (dy ? 0 : 1);
            const int ix = X + (j % 3) - (dxp ? 0 : 1);
            if (iy >= r0 && iy < r0 + 6 && (unsigned)ix < 14u) {
                const half4 dv = *(const half4*)&ds[((iy - r0) * 14 + ix) * 256 + ch0];
                const half4 w4 = wp[j];
                half2v dlo = {dv.x, dv.y}, dhi = {dv.z, dv.w};
                half2v wlo = {w4.x, w4.y}, whi = {w4.z, w4.w};
                acc = __builtin_amdgcn_fdot2(dlo, wlo, acc, false);
                acc = __builtin_amdgcn_fdot2(dhi, whi, acc, false);
            }
        }
#pragma unroll
        for (int off = 32; off; off >>= 1) acc += __shfl_xor(acc, off);
        if (lane == 0) out[(size_t)b * 784 + oy * 28 + ox] = 1.f / (1.f + expf(-(acc + bv)));
    }
}

extern "C" void kernel_launch(void* const* d_in, const int* in_sizes, int n_in,
                              void* d_out, int out_size, void* d_ws, size_t ws_size,
                              hipStream_t stream) {
    const float* x    = (const float*)d_in[0];
    const float* c1w  = (const float*)d_in[1];
    const float* c1b  = (const float*)d_in[2];
    const float* c2w  = (const float*)d_in[3];
    const float* c2b  = (const float*)d_in[4];
    const float* ew   = (const float*)d_in[5];
    const float* eb   = (const float*)d_in[6];
    const float* emb  = (const float*)d_in[7];
    const float* dw   = (const float*)d_in[8];
    const float* db   = (const float*)d_in[9];
    const float* dc1w = (const float*)d_in[10];
    const float* dc1b = (const float*)d_in[11];
    const float* dc2w = (const float*)d_in[12];
    const float* dc2b = (const float*)d_in[13];
    float* out = (float*)d_out;

    char* ws = (char*)d_ws;
    size_t off = 0;
    auto alloc = [&](size_t bytes) { size_t o = off; off += (bytes + 255) & ~(size_t)255; return o; };

    u16*      h1p_hi = (u16*)(ws + alloc((size_t)256 * 196 * 256 * 2));
    u16*      h1p_lo = (u16*)(ws + alloc((size_t)256 * 196 * 256 * 2));
    u16*      w2T_hi = (u16*)(ws + alloc((size_t)16 * 256 * 256 * 2));
    u16*      w2T_lo = (u16*)(ws + alloc((size_t)16 * 256 * 256 * 2));
    float*    h2     = (float*)(ws + alloc((size_t)256 * 196 * 256 * 4));
    float*    h2p    = (float*)(ws + alloc((size_t)256 * 49 * 256 * 4));
    float*    zcat   = (float*)(ws + alloc((size_t)512 * 64 * 4));
    _Float16* dech   = (_Float16*)(ws + alloc((size_t)512 * 49 * 256 * 2));
    _Float16* wc1    = (_Float16*)(ws + alloc((size_t)25 * 256 * 256 * 2));
    _Float16* d1     = (_Float16*)(ws + alloc((size_t)512 * 196 * 256 * 2));
    _Float16* w2c    = (_Float16*)(ws + alloc((size_t)9216 * 2));
    u16*      zg     = (u16*)(ws + alloc(256));
    float*    partials = h2;                            // h2 is dead after pool2

    hipMemsetAsync(zg, 0, 256, stream);
    wprep_split_kernel<<<4096, 256, 0, stream>>>(c2w, w2T_hi, w2T_lo);
    wprep_dc1_par<<<6400, 256, 0, stream>>>(dc1w, wc1);
    wprep_dc2_par<<<36, 256, 0, stream>>>(dc2w, w2c);
    conv1_pool_v2<<<3584, 256, 0, stream>>>(x, c1w, c1b, h1p_hi, h1p_lo);
    conv2_split_v2<<<dim3(392, 2), 256, 0, stream>>>(h1p_hi, h1p_lo, w2T_hi, w2T_lo, zg, c2b, h2);
    pool2_kernel<<<12544, 256, 0, stream>>>(h2, h2p);
    encp_kernel<<<98, 256, 0, stream>>>(h2p, ew, partials);
    encr_kernel<<<64, 256, 0, stream>>>(partials, eb, zcat);
    som_kernel<<<256, 256, 0, stream>>>(emb, zcat);
    dec_kernel<<<3136, 256, 0, stream>>>(zcat, dw, db, dech);
    deconv1_par<<<dim3(196, 2, 4), 256, 0, stream>>>(dech, wc1, (const _Float16*)zg, dc1b, d1);
    deconv2_v5<<<2048, 256, 0, stream>>>(d1, w2c, dc2b, out);
}

// Round 7
// 881.149 us; speedup vs baseline: 1.2297x; 1.1347x over previous
//
#include <hip/hip_runtime.h>
#include <hip/hip_bf16.h>

typedef unsigned short u16;
using short8 = __attribute__((ext_vector_type(8))) short;
using half8  = __attribute__((ext_vector_type(8))) _Float16;
using half4  = __attribute__((ext_vector_type(4))) _Float16;
using half2v = __attribute__((ext_vector_type(2))) _Float16;
using f32x4  = __attribute__((ext_vector_type(4))) float;

__device__ __forceinline__ u16 f2bf(float f) {
    unsigned int u = __float_as_uint(f);
    u += 0x7FFFu + ((u >> 16) & 1u);   // RNE
    return (u16)(u >> 16);
}
__device__ __forceinline__ float bf2f(u16 h) {
    return __uint_as_float(((unsigned int)h) << 16);
}

__device__ __forceinline__ void gl_lds16(const void* g, void* l) {
    __builtin_amdgcn_global_load_lds((const __attribute__((address_space(1))) void*)g,
                                     (__attribute__((address_space(3))) void*)l, 16, 0, 0);
}

#define PIPE_WAIT8() asm volatile("s_waitcnt vmcnt(8)" ::: "memory")
#define PIPE_WAIT0() asm volatile("s_waitcnt vmcnt(0)" ::: "memory")
#define BAR() __builtin_amdgcn_s_barrier()

// ---------------- weight prep: conv2 HWIO -> [kk][n][ci], split bf16 hi/lo ----------------
__global__ __launch_bounds__(256) void wprep_split_kernel(const float* __restrict__ src,
                                                          u16* __restrict__ hi, u16* __restrict__ lo) {
    int idx = blockIdx.x * 256 + threadIdx.x;          // 16*256*256
    int ci = idx & 255, n = (idx >> 8) & 255, kk = idx >> 16;
    float v = src[(kk * 256 + ci) * 256 + n];
    u16 h = f2bf(v);
    hi[idx] = h;
    lo[idx] = f2bf(v - bf2f(h));
}

// ---------------- weight prep: deconv1 parity-combined -> [tap_g][n][ci] fp16 (25 taps) ----------------
__global__ __launch_bounds__(256) void wprep_dc1_par(const float* __restrict__ src, _Float16* __restrict__ dst) {
    const int idx = blockIdx.x * 256 + threadIdx.x;    // 25*65536
    const int ci = idx & 255, n = (idx >> 8) & 255, tg = idx >> 16;
    int p, j;
    if (tg < 9)       { p = 0; j = tg; }
    else if (tg < 15) { p = 1; j = tg - 9; }
    else if (tg < 21) { p = 2; j = tg - 15; }
    else              { p = 3; j = tg - 21; }
    const int dy = p >> 1, dx = p & 1;
    const int nx = 3 - dx;
    const int oyi = j / nx, oxi = j % nx;
    int ky0, kyn, kx0, kxn;
    if (dy == 0) { ky0 = (oyi == 0) ? 0 : (oyi == 1 ? 1 : 3); kyn = (oyi == 1) ? 2 : 1; }
    else         { ky0 = (oyi == 0) ? 0 : 2;                  kyn = 2; }
    if (dx == 0) { kx0 = (oxi == 0) ? 0 : (oxi == 1 ? 1 : 3); kxn = (oxi == 1) ? 2 : 1; }
    else         { kx0 = (oxi == 0) ? 0 : 2;                  kxn = 2; }
    float s = 0.f;
    for (int a = 0; a < kyn; ++a)
        for (int c = 0; c < kxn; ++c)
            s += src[(((ky0 + a) * 4 + (kx0 + c)) * 256 + ci) * 256 + n];
    dst[((size_t)tg << 16) + (n << 8) + ci] = (_Float16)s;
}

// ---------------- weight prep: deconv2 parity-combined -> [p][9][256] fp16 (zero-padded taps) ----------------
__global__ __launch_bounds__(256) void wprep_dc2_par(const float* __restrict__ src, _Float16* __restrict__ dst) {
    const int idx = blockIdx.x * 256 + threadIdx.x;    // 36*256 = 9216
    if (idx >= 9216) return;
    const int ci = idx & 255;
    const int j9 = (idx >> 8) % 9, p = (idx >> 8) / 9;
    const int dy = p >> 1, dx = p & 1;
    const int oyi = j9 / 3, oxi = j9 % 3;
    float s = 0.f;
    if (!((dy == 1 && oyi == 2) || (dx == 1 && oxi == 2))) {
        int ky0, kyn, kx0, kxn;
        if (dy == 0) { ky0 = (oyi == 0) ? 0 : (oyi == 1 ? 1 : 3); kyn = (oyi == 1) ? 2 : 1; }
        else         { ky0 = (oyi == 0) ? 0 : 2;                  kyn = 2; }
        if (dx == 0) { kx0 = (oxi == 0) ? 0 : (oxi == 1 ? 1 : 3); kxn = (oxi == 1) ? 2 : 1; }
        else         { kx0 = (oxi == 0) ? 0 : 2;                  kxn = 2; }
        for (int a = 0; a < kyn; ++a)
            for (int c = 0; c < kxn; ++c)
                s += src[((ky0 + a) * 4 + (kx0 + c)) * 256 + ci];
    }
    dst[idx] = (_Float16)s;
}

// ---------------- conv1 (1->256) + ReLU + maxpool, block = (b, pooled row) ----------------
__global__ __launch_bounds__(256) void conv1_pool_v2(const float* __restrict__ x,
                                                     const float* __restrict__ w,
                                                     const float* __restrict__ bias,
                                                     u16* __restrict__ hi, u16* __restrict__ lo) {
    __shared__ float xs[5][32];
    const int blk = blockIdx.x;                         // b*14 + py
    const int py = blk % 14, b = blk / 14;
    const int t = threadIdx.x;
    for (int i = t; i < 160; i += 256) {
        const int r = i >> 5, c = i & 31;
        const int gy = 2 * py - 1 + r, gx = c - 1;
        float v = 0.f;
        if ((unsigned)gy < 28u && (unsigned)gx < 28u) v = x[(b * 28 + gy) * 28 + gx];
        xs[r][c] = v;
    }
    __syncthreads();
    float wr[16];
#pragma unroll
    for (int k = 0; k < 16; ++k) wr[k] = w[k * 256 + t];
    const float bs = bias[t];
    for (int px = 0; px < 14; ++px) {
        float m = 0.f;
#pragma unroll
        for (int dy = 0; dy < 2; ++dy)
#pragma unroll
            for (int dx = 0; dx < 2; ++dx) {
                float a = bs;
#pragma unroll
                for (int ky = 0; ky < 4; ++ky)
#pragma unroll
                    for (int kx = 0; kx < 4; ++kx)
                        a += xs[dy + ky][2 * px + dx + kx] * wr[ky * 4 + kx];
                m = fmaxf(m, a);
            }
        u16 h = f2bf(m);
        const int o = ((b * 14 + py) * 14 + px) * 256 + t;
        hi[o] = h;
        lo[o] = f2bf(m - bf2f(h));
    }
}

// ---------------- conv2 v2 (best known): 128x128 tile, global_load_lds + XOR-swizzle, split-bf16 3-pass ----------------
// M = 50176, N = 256, K = 16 x 256.  Grid (392, 2), 256 threads (4 waves, each owns 64x64).
__global__ __launch_bounds__(256, 2) void conv2_split_v2(const u16* __restrict__ Ih, const u16* __restrict__ Il,
                                                         const u16* __restrict__ Wh, const u16* __restrict__ Wl,
                                                         const u16* __restrict__ zg,
                                                         const float* __restrict__ bias, float* __restrict__ out) {
    __shared__ __align__(16) short lds[32768];          // AH 0, AL 8192, BH 16384, BL 24576 (64 KiB)
    const int AL = 8192, BH = 16384, BL = 24576;
    const int t = threadIdx.x, lane = t & 63, w = t >> 6;
    const int wm = w >> 1, wn = w & 1;
    const int l16 = lane & 15, l4 = lane >> 4;
    const int m0 = blockIdx.x * 128, n0 = blockIdx.y * 128;
    // staging geometry: wave w stages rows 32w..32w+31 of each array; instr j covers 8 rows.
    const int rl = lane >> 3;                           // row within 8-group (== row&7)
    const int chS = (((lane & 7) ^ rl)) << 3;           // source chunk offset in shorts (16B units)
    int ay[4], ax[4], ab[4], wb[4], aoff[4];
    bool av[4];
#pragma unroll
    for (int j = 0; j < 4; ++j) {
        const int r = w * 32 + j * 8 + rl;
        const int gm = m0 + r;
        const int b = gm / 196, rem = gm % 196;
        ay[j] = rem / 14; ax[j] = rem % 14; ab[j] = b * 196;
        wb[j] = (n0 + r) << 8;
    }
    f32x4 acc[4][4] = {};

    for (int kt = 0; kt < 64; ++kt) {
        const int kk = kt >> 2;
        if ((kt & 3) == 0) {
            const int ky = kk >> 2, kx = kk & 3;
#pragma unroll
            for (int j = 0; j < 4; ++j) {
                const int iy = ay[j] + ky - 1, ix = ax[j] + kx - 1;
                av[j] = ((unsigned)iy < 14u) && ((unsigned)ix < 14u);
                aoff[j] = (ab[j] + iy * 14 + ix) << 8;
            }
        }
        const int kc = (kt & 3) << 6;
        __syncthreads();
#pragma unroll
        for (int j = 0; j < 4; ++j) {
            const int rowb = (w * 32 + j * 8) << 6;     // row*64 shorts
            const u16* gh = av[j] ? (Ih + aoff[j] + kc + chS) : zg;
            const u16* gl = av[j] ? (Il + aoff[j] + kc + chS) : zg;
            gl_lds16(gh, lds + rowb);
            gl_lds16(gl, lds + AL + rowb);
            const int woff = (kk << 16) + wb[j] + kc + chS;
            gl_lds16(Wh + woff, lds + BH + rowb);
            gl_lds16(Wl + woff, lds + BL + rowb);
        }
        __syncthreads();
#pragma unroll
        for (int ks = 0; ks < 2; ++ks) {
            short8 bhf[4], blf[4];
#pragma unroll
            for (int ni = 0; ni < 4; ++ni) {
                const int row = wn * 64 + ni * 16 + l16;
                const int p = (ks * 4 + l4) ^ (row & 7);
                const int off = (row << 6) + (p << 3);
                bhf[ni] = *(const short8*)&lds[BH + off];
                blf[ni] = *(const short8*)&lds[BL + off];
            }
#pragma unroll
            for (int mi = 0; mi < 4; ++mi) {
                const int row = wm * 64 + mi * 16 + l16;
                const int p = (ks * 4 + l4) ^ (row & 7);
                const int off = (row << 6) + (p << 3);
                const short8 ah = *(const short8*)&lds[off];
                const short8 al = *(const short8*)&lds[AL + off];
#pragma unroll
                for (int ni = 0; ni < 4; ++ni) {
                    acc[mi][ni] = __builtin_amdgcn_mfma_f32_16x16x32_bf16(ah, bhf[ni], acc[mi][ni], 0, 0, 0);
                    acc[mi][ni] = __builtin_amdgcn_mfma_f32_16x16x32_bf16(ah, blf[ni], acc[mi][ni], 0, 0, 0);
                    acc[mi][ni] = __builtin_amdgcn_mfma_f32_16x16x32_bf16(al, bhf[ni], acc[mi][ni], 0, 0, 0);
                }
            }
        }
    }
#pragma unroll
    for (int ni = 0; ni < 4; ++ni) {
        const int col = n0 + wn * 64 + ni * 16 + l16;
        const float bv = bias[col];
#pragma unroll
        for (int mi = 0; mi < 4; ++mi) {
            const int mrow = m0 + wm * 64 + mi * 16 + l4 * 4;
#pragma unroll
            for (int r = 0; r < 4; ++r)
                out[(size_t)(mrow + r) * 256 + col] = fmaxf(acc[mi][ni][r] + bv, 0.f);
        }
    }
}

// ---------------- deconv1 parity GEMM: 16x16x32 fp16, counted-vmcnt 2-buffer ----------------
// M=25088, N=256, K=ntaps(p)x256. Grid (196, 2, 4). Output to upsampled 14x14 grid (2Y+dy, 2X+dx).
__global__ __launch_bounds__(256, 2) void deconv1_par(const _Float16* __restrict__ I,
                                                      const _Float16* __restrict__ WC,
                                                      const _Float16* __restrict__ zg,
                                                      const float* __restrict__ bias,
                                                      _Float16* __restrict__ out) {
    __shared__ __align__(16) _Float16 lds[32768];       // 64KB: 2 bufs x (A 8192 | B 8192) halfs
    const int t = threadIdx.x, lane = t & 63, w = t >> 6;
    const int wm = w >> 1, wn = w & 1;
    const int l16 = lane & 15, l4 = lane >> 4;
    const int m0 = blockIdx.x * 128, n0 = blockIdx.y * 128;
    const int p = blockIdx.z, dy = p >> 1, dx = p & 1;
    const int nx = 3 - dx;
    const int ntaps = (3 - dy) * nx;
    const int pbase = (dy == 0) ? (dx == 0 ? 0 : 9) : (dx == 0 ? 15 : 21);
    const int nkt = ntaps * 4;

    const int rl8 = lane >> 3;
    const int g = (lane & 7) ^ rl8;
    const _Float16* selA = I + (g << 3);
    const _Float16* selB = WC + ((size_t)pbase << 16) + (g << 3);

    int aY[4], aX[4], ab[4], wb[4];
#pragma unroll
    for (int j = 0; j < 4; ++j) {
        const int r = w * 32 + j * 8 + rl8;
        const int gm = m0 + r;
        const int b = gm / 49, rem = gm % 49;
        aY[j] = rem / 7; aX[j] = rem % 7; ab[j] = b * 49;
        wb[j] = (n0 + r) << 8;
    }
    int aoff[4]; bool av[4];
    auto dectap = [&](int kk) {
        const int oy = kk / nx - (dy == 0 ? 1 : 0);
        const int ox = kk % nx - (dx == 0 ? 1 : 0);
#pragma unroll
        for (int j = 0; j < 4; ++j) {
            const int iy = aY[j] + oy, ix = aX[j] + ox;
            av[j] = ((unsigned)iy < 7u) && ((unsigned)ix < 7u);
            aoff[j] = (ab[j] + iy * 7 + ix) << 8;
        }
    };
    int rdA[4], rdB[4];
#pragma unroll
    for (int mi = 0; mi < 4; ++mi) {
        const int ra = wm * 64 + mi * 16 + l16;
        rdA[mi] = (ra << 6) + ((l4 ^ (ra & 7)) << 3);
    }
#pragma unroll
    for (int ni = 0; ni < 4; ++ni) {
        const int rb = wn * 64 + ni * 16 + l16;
        rdB[ni] = 8192 + (rb << 6) + ((l4 ^ (rb & 7)) << 3);
    }
    auto stage = [&](int kt) {
        const int kk = kt >> 2, kc = (kt & 3) << 6;
        const int buf = (kt & 1) << 14;
#pragma unroll
        for (int j = 0; j < 4; ++j) {
            const int rowb = buf + ((w * 32 + j * 8) << 6);
            const _Float16* asrc = av[j] ? (selA + aoff[j] + kc) : zg;
            gl_lds16(asrc, lds + rowb);
            gl_lds16(selB + (kk << 16) + wb[j] + kc, lds + 8192 + rowb);
        }
    };

    f32x4 acc[4][4] = {};
    dectap(0);
    stage(0);
    for (int kt = 0; kt < nkt; ++kt) {
        const int ktn = (kt < nkt - 1) ? kt + 1 : kt;
        if ((ktn & 3) == 0 && ktn == kt + 1) dectap(ktn >> 2);
        stage(ktn);
        PIPE_WAIT8();
        BAR();
        const int base = (kt & 1) << 14;
#pragma unroll
        for (int ks = 0; ks < 2; ++ks) {
            const int x32 = ks << 5;
            half8 b8[4];
#pragma unroll
            for (int ni = 0; ni < 4; ++ni)
                b8[ni] = *(const half8*)&lds[base + (rdB[ni] ^ x32)];
#pragma unroll
            for (int mi = 0; mi < 4; ++mi) {
                const half8 a8 = *(const half8*)&lds[base + (rdA[mi] ^ x32)];
#pragma unroll
                for (int ni = 0; ni < 4; ++ni)
                    acc[mi][ni] = __builtin_amdgcn_mfma_f32_16x16x32_f16(a8, b8[ni], acc[mi][ni], 0, 0, 0);
            }
        }
        BAR();
    }
    PIPE_WAIT0();
#pragma unroll
    for (int mi = 0; mi < 4; ++mi) {
        const int mb = m0 + wm * 64 + mi * 16 + l4 * 4;
#pragma unroll
        for (int r = 0; r < 4; ++r) {
            const int m = mb + r;
            const int b = m / 49, rem = m % 49;
            const int Y = rem / 7, X = rem % 7;
            _Float16* op = out + (((size_t)(b * 196 + (2 * Y + dy) * 14 + (2 * X + dx))) << 8);
#pragma unroll
            for (int ni = 0; ni < 4; ++ni) {
                const int col = n0 + wn * 64 + ni * 16 + l16;
                op[col] = (_Float16)fmaxf(acc[mi][ni][r] + bias[col], 0.f);
            }
        }
    }
}

// ---------------- maxpool 2x2 on h2 (f32) -> h2p ----------------
__global__ __launch_bounds__(256) void pool2_kernel(const float* __restrict__ h2, float* __restrict__ h2p) {
    int idx = blockIdx.x * 256 + threadIdx.x;           // 256*49*256
    int c = idx & 255;
    int rest = idx >> 8;
    int px = rest % 7, py = (rest / 7) % 7, b = rest / 49;
    const float* base = h2 + (((size_t)(b * 14 + 2 * py)) * 14 + 2 * px) * 256 + c;
    float v = fmaxf(fmaxf(base[0], base[256]), fmaxf(base[14 * 256], base[14 * 256 + 256]));
    h2p[idx] = v;
}

// ---------------- encoder split-K stage 1: 98 k-slices of 128, ew read once ----------------
__global__ __launch_bounds__(256) void encp_kernel(const float* __restrict__ h2p, const float* __restrict__ ew,
                                                   float* __restrict__ partials) {
    __shared__ float ews[8192];                         // [128 k][64 n]
    __shared__ float hbuf[8][128];
    const int t = threadIdx.x, c = blockIdx.x;
    const float* esrc = ew + (size_t)c * 8192;
    for (int i = t; i < 2048; i += 256)
        *(f32x4*)&ews[i * 4] = *(const f32x4*)&esrc[i * 4];
    const int n = t & 63, sub = t >> 6;
    const int rr = t >> 5, kq = (t & 31) << 2;
    float* pout = partials + (size_t)c * 16384;
    for (int bi = 0; bi < 32; ++bi) {
        __syncthreads();
        *(f32x4*)&hbuf[rr][kq] = *(const f32x4*)&h2p[(size_t)(bi * 8 + rr) * 12544 + c * 128 + kq];
        __syncthreads();
        float a0 = 0.f, a1 = 0.f;
        for (int k = 0; k < 128; ++k) {
            const float wv = ews[k * 64 + n];
            a0 += hbuf[sub][k] * wv;
            a1 += hbuf[sub + 4][k] * wv;
        }
        pout[(bi * 8 + sub) * 64 + n] = a0;
        pout[(bi * 8 + sub + 4) * 64 + n] = a1;
    }
}

// ---------------- encoder stage 2: reduce 98 partials + bias -> zcat rows 0..255 ----------------
__global__ __launch_bounds__(256) void encr_kernel(const float* __restrict__ partials, const float* __restrict__ eb,
                                                   float* __restrict__ zcat) {
    const int o = blockIdx.x * 256 + threadIdx.x;       // 16384
    float s = eb[o & 63];
    for (int c = 0; c < 98; ++c) s += partials[(size_t)c * 16384 + o];
    zcat[o] = s;
}

// ---------------- SOM argmin ----------------
__global__ __launch_bounds__(256) void som_kernel(const float* __restrict__ emb, float* __restrict__ zcat) {
    __shared__ float zrow[64];
    __shared__ float sd[256];
    __shared__ int si[256];
    const int b = blockIdx.x, t = threadIdx.x;
    if (t < 64) zrow[t] = zcat[b * 64 + t];
    __syncthreads();
    float acc = 0.f;
    const float* e = emb + t * 64;
    for (int d = 0; d < 64; ++d) { float df = zrow[d] - e[d]; acc += df * df; }
    sd[t] = acc; si[t] = t;
    __syncthreads();
    for (int off = 128; off >= 1; off >>= 1) {
        if (t < off) {
            float d2 = sd[t + off]; int i2 = si[t + off];
            if (d2 < sd[t] || (d2 == sd[t] && i2 < si[t])) { sd[t] = d2; si[t] = i2; }
        }
        __syncthreads();
    }
    const int k = si[0];
    if (t < 64) zcat[(256 + b) * 64 + t] = emb[k * 64 + t];
}

// ---------------- decoder linear ----------------
__global__ __launch_bounds__(256) void dec_kernel(const float* __restrict__ zcat, const float* __restrict__ dw,
                                                  const float* __restrict__ db, _Float16* __restrict__ dech) {
    __shared__ float z[8][64];
    const int t = threadIdx.x;
    const int bg = blockIdx.x / 49;
    const int nc = blockIdx.x % 49;
    for (int i = t; i < 512; i += 256) z[i >> 6][i & 63] = zcat[bg * 512 + i];
    __syncthreads();
    const int n = nc * 256 + t;
    const float bv = db[n];
    float acc[8];
#pragma unroll
    for (int j = 0; j < 8; ++j) acc[j] = bv;
    for (int k = 0; k < 64; ++k) {
        float wv = dw[(size_t)k * 12544 + n];
#pragma unroll
        for (int j = 0; j < 8; ++j) acc[j] += z[j][k] * wv;
    }
#pragma unroll
    for (int j = 0; j < 8; ++j) dech[((size_t)(bg * 8 + j)) * 12544 + n] = (_Float16)acc[j];
}

// ---------------- deconv2 v6: quarter-image blocks, weights in LDS (fixes rule-#20 scratch), sigmoid ----------------
// Block = (b, q), q in 0..3 -> output rows oy = 7q..7q+6. Staged d1 rows r0..r0+5, r0 = min(3q, 8).
__global__ __launch_bounds__(256) void deconv2_v6(const _Float16* __restrict__ d1, const _Float16* __restrict__ w2c,
                                                  const float* __restrict__ bias, float* __restrict__ out) {
    __shared__ _Float16 ds[6 * 14 * 256];               // 42KB input rows
    __shared__ _Float16 wl[9216];                       // 18KB [p][9][256] weights (runtime-indexed: LDS, not regs!)
    const int t = threadIdx.x;
    const int blk = blockIdx.x;                         // 512 b x 4 quarters
    const int q = blk & 3, b = blk >> 2;
    const int r0 = (q == 3) ? 8 : 3 * q;
    for (int i = t; i < 1152; i += 256)                 // 9216 halfs / 8
        *(half8*)&wl[i * 8] = *(const half8*)&w2c[i * 8];
    for (int i = t; i < 2688; i += 256) {               // 6 rows x 448 half8 units
        const int r = i / 448, rem = i % 448;
        *(half8*)&ds[r * 3584 + rem * 8] =
            *(const half8*)&d1[((size_t)(b * 14 + r0 + r) * 14) * 256 + rem * 8];
    }
    const int lane = t & 63, wv = t >> 6;
    const int ch0 = lane * 4;
    const float bv = bias[0];
    __syncthreads();
    for (int pi = 0; pi < 49; ++pi) {
        const int ql = pi * 4 + wv;                     // 196 px per quarter
        const int oy = 7 * q + ql / 28, ox = ql % 28;
        const int dy = oy & 1, Y = oy >> 1;
        const int dxp = ox & 1, X = ox >> 1;
        const _Float16* wp = &wl[((dy * 2 + dxp) * 9) * 256 + ch0];
        float a0 = 0.f, a1 = 0.f;
#pragma unroll
        for (int j = 0; j < 9; ++j) {
            const int iy = Y + (j / 3) - (dy ? 0 : 1);
            const int ix = X + (j % 3) - (dxp ? 0 : 1);
            if (iy >= r0 && iy < r0 + 6 && (unsigned)ix < 14u) {
                const half4 dv = *(const half4*)&ds[((iy - r0) * 14 + ix) * 256 + ch0];
                const half4 w4 = *(const half4*)&wp[j * 256];
                half2v dlo = {dv.x, dv.y}, dhi = {dv.z, dv.w};
                half2v wlo = {w4.x, w4.y}, whi = {w4.z, w4.w};
                a0 = __builtin_amdgcn_fdot2(dlo, wlo, a0, false);
                a1 = __builtin_amdgcn_fdot2(dhi, whi, a1, false);
            }
        }
        float acc = a0 + a1;
#pragma unroll
        for (int off = 32; off; off >>= 1) acc += __shfl_xor(acc, off);
        if (lane == 0) out[(size_t)b * 784 + oy * 28 + ox] = 1.f / (1.f + expf(-(acc + bv)));
    }
}

extern "C" void kernel_launch(void* const* d_in, const int* in_sizes, int n_in,
                              void* d_out, int out_size, void* d_ws, size_t ws_size,
                              hipStream_t stream) {
    const float* x    = (const float*)d_in[0];
    const float* c1w  = (const float*)d_in[1];
    const float* c1b  = (const float*)d_in[2];
    const float* c2w  = (const float*)d_in[3];
    const float* c2b  = (const float*)d_in[4];
    const float* ew   = (const float*)d_in[5];
    const float* eb   = (const float*)d_in[6];
    const float* emb  = (const float*)d_in[7];
    const float* dw   = (const float*)d_in[8];
    const float* db   = (const float*)d_in[9];
    const float* dc1w = (const float*)d_in[10];
    const float* dc1b = (const float*)d_in[11];
    const float* dc2w = (const float*)d_in[12];
    const float* dc2b = (const float*)d_in[13];
    float* out = (float*)d_out;

    char* ws = (char*)d_ws;
    size_t off = 0;
    auto alloc = [&](size_t bytes) { size_t o = off; off += (bytes + 255) & ~(size_t)255; return o; };

    u16*      h1p_hi = (u16*)(ws + alloc((size_t)256 * 196 * 256 * 2));
    u16*      h1p_lo = (u16*)(ws + alloc((size_t)256 * 196 * 256 * 2));
    u16*      w2T_hi = (u16*)(ws + alloc((size_t)16 * 256 * 256 * 2));
    u16*      w2T_lo = (u16*)(ws + alloc((size_t)16 * 256 * 256 * 2));
    float*    h2     = (float*)(ws + alloc((size_t)256 * 196 * 256 * 4));
    float*    h2p    = (float*)(ws + alloc((size_t)256 * 49 * 256 * 4));
    float*    zcat   = (float*)(ws + alloc((size_t)512 * 64 * 4));
    _Float16* dech   = (_Float16*)(ws + alloc((size_t)512 * 49 * 256 * 2));
    _Float16* wc1    = (_Float16*)(ws + alloc((size_t)25 * 256 * 256 * 2));
    _Float16* d1     = (_Float16*)(ws + alloc((size_t)512 * 196 * 256 * 2));
    _Float16* w2c    = (_Float16*)(ws + alloc((size_t)9216 * 2));
    u16*      zg     = (u16*)(ws + alloc(256));
    float*    partials = h2;                            // h2 is dead after pool2

    hipMemsetAsync(zg, 0, 256, stream);
    wprep_split_kernel<<<4096, 256, 0, stream>>>(c2w, w2T_hi, w2T_lo);
    wprep_dc1_par<<<6400, 256, 0, stream>>>(dc1w, wc1);
    wprep_dc2_par<<<36, 256, 0, stream>>>(dc2w, w2c);
    conv1_pool_v2<<<3584, 256, 0, stream>>>(x, c1w, c1b, h1p_hi, h1p_lo);
    conv2_split_v2<<<dim3(392, 2), 256, 0, stream>>>(h1p_hi, h1p_lo, w2T_hi, w2T_lo, zg, c2b, h2);
    pool2_kernel<<<12544, 256, 0, stream>>>(h2, h2p);
    encp_kernel<<<98, 256, 0, stream>>>(h2p, ew, partials);
    encr_kernel<<<64, 256, 0, stream>>>(partials, eb, zcat);
    som_kernel<<<256, 256, 0, stream>>>(emb, zcat);
    dec_kernel<<<3136, 256, 0, stream>>>(zcat, dw, db, dech);
    deconv1_par<<<dim3(196, 2, 4), 256, 0, stream>>>(dech, wc1, (const _Float16*)zg, dc1b, d1);
    deconv2_v6<<<2048, 256, 0, stream>>>(d1, w2c, dc2b, out);
}

// Round 8
// 859.448 us; speedup vs baseline: 1.2608x; 1.0252x over previous
//
#include <hip/hip_runtime.h>
#include <hip/hip_bf16.h>

typedef unsigned short u16;
using short8 = __attribute__((ext_vector_type(8))) short;
using half8  = __attribute__((ext_vector_type(8))) _Float16;
using half4  = __attribute__((ext_vector_type(4))) _Float16;
using half2v = __attribute__((ext_vector_type(2))) _Float16;
using f32x4  = __attribute__((ext_vector_type(4))) float;

__device__ __forceinline__ u16 f2bf(float f) {
    unsigned int u = __float_as_uint(f);
    u += 0x7FFFu + ((u >> 16) & 1u);   // RNE
    return (u16)(u >> 16);
}
__device__ __forceinline__ float bf2f(u16 h) {
    return __uint_as_float(((unsigned int)h) << 16);
}

__device__ __forceinline__ void gl_lds16(const void* g, void* l) {
    __builtin_amdgcn_global_load_lds((const __attribute__((address_space(1))) void*)g,
                                     (__attribute__((address_space(3))) void*)l, 16, 0, 0);
}

// ---------------- fused weight prep: conv2 split / deconv1 parity / deconv2 parity / zg zero ----------------
__global__ __launch_bounds__(256) void wprep_all(const float* __restrict__ c2w,
                                                 u16* __restrict__ hi, u16* __restrict__ lo,
                                                 const float* __restrict__ dc1w, _Float16* __restrict__ wc1,
                                                 const float* __restrict__ dc2w, _Float16* __restrict__ w2c,
                                                 u16* __restrict__ zg) {
    const int bid = blockIdx.x, t = threadIdx.x;
    if (bid < 4096) {                                   // conv2 HWIO -> [kk][n][ci], split bf16 hi/lo
        int idx = bid * 256 + t;
        int ci = idx & 255, n = (idx >> 8) & 255, kk = idx >> 16;
        float v = c2w[(kk * 256 + ci) * 256 + n];
        u16 h = f2bf(v);
        hi[idx] = h;
        lo[idx] = f2bf(v - bf2f(h));
    } else if (bid < 10496) {                           // deconv1 parity-combined (25 tap-groups)
        const int idx = (bid - 4096) * 256 + t;
        const int ci = idx & 255, n = (idx >> 8) & 255, tg = idx >> 16;
        int p, j;
        if (tg < 9)       { p = 0; j = tg; }
        else if (tg < 15) { p = 1; j = tg - 9; }
        else if (tg < 21) { p = 2; j = tg - 15; }
        else              { p = 3; j = tg - 21; }
        const int dy = p >> 1, dx = p & 1;
        const int nx = 3 - dx;
        const int oyi = j / nx, oxi = j % nx;
        int ky0, kyn, kx0, kxn;
        if (dy == 0) { ky0 = (oyi == 0) ? 0 : (oyi == 1 ? 1 : 3); kyn = (oyi == 1) ? 2 : 1; }
        else         { ky0 = (oyi == 0) ? 0 : 2;                  kyn = 2; }
        if (dx == 0) { kx0 = (oxi == 0) ? 0 : (oxi == 1 ? 1 : 3); kxn = (oxi == 1) ? 2 : 1; }
        else         { kx0 = (oxi == 0) ? 0 : 2;                  kxn = 2; }
        float s = 0.f;
        for (int a = 0; a < kyn; ++a)
            for (int c = 0; c < kxn; ++c)
                s += dc1w[(((ky0 + a) * 4 + (kx0 + c)) * 256 + ci) * 256 + n];
        wc1[((size_t)tg << 16) + (n << 8) + ci] = (_Float16)s;
    } else if (bid < 10532) {                           // deconv2 parity-combined [p][9][256]
        const int idx = (bid - 10496) * 256 + t;
        if (idx >= 9216) return;
        const int ci = idx & 255;
        const int j9 = (idx >> 8) % 9, p = (idx >> 8) / 9;
        const int dy = p >> 1, dx = p & 1;
        const int oyi = j9 / 3, oxi = j9 % 3;
        float s = 0.f;
        if (!((dy == 1 && oyi == 2) || (dx == 1 && oxi == 2))) {
            int ky0, kyn, kx0, kxn;
            if (dy == 0) { ky0 = (oyi == 0) ? 0 : (oyi == 1 ? 1 : 3); kyn = (oyi == 1) ? 2 : 1; }
            else         { ky0 = (oyi == 0) ? 0 : 2;                  kyn = 2; }
            if (dx == 0) { kx0 = (oxi == 0) ? 0 : (oxi == 1 ? 1 : 3); kxn = (oxi == 1) ? 2 : 1; }
            else         { kx0 = (oxi == 0) ? 0 : 2;                  kxn = 2; }
            for (int a = 0; a < kyn; ++a)
                for (int c = 0; c < kxn; ++c)
                    s += dc2w[((ky0 + a) * 4 + (kx0 + c)) * 256 + ci];
        }
        w2c[idx] = (_Float16)s;
    } else {                                            // zero guard page
        if (t < 128) zg[t] = 0;
    }
}

// ---------------- conv1 (1->256) + ReLU + maxpool, block = (b, pooled row) ----------------
__global__ __launch_bounds__(256) void conv1_pool_v2(const float* __restrict__ x,
                                                     const float* __restrict__ w,
                                                     const float* __restrict__ bias,
                                                     u16* __restrict__ hi, u16* __restrict__ lo) {
    __shared__ float xs[5][32];
    const int blk = blockIdx.x;                         // b*14 + py
    const int py = blk % 14, b = blk / 14;
    const int t = threadIdx.x;
    for (int i = t; i < 160; i += 256) {
        const int r = i >> 5, c = i & 31;
        const int gy = 2 * py - 1 + r, gx = c - 1;
        float v = 0.f;
        if ((unsigned)gy < 28u && (unsigned)gx < 28u) v = x[(b * 28 + gy) * 28 + gx];
        xs[r][c] = v;
    }
    __syncthreads();
    float wr[16];
#pragma unroll
    for (int k = 0; k < 16; ++k) wr[k] = w[k * 256 + t];
    const float bs = bias[t];
    for (int px = 0; px < 14; ++px) {
        float m = 0.f;
#pragma unroll
        for (int dy = 0; dy < 2; ++dy)
#pragma unroll
            for (int dx = 0; dx < 2; ++dx) {
                float a = bs;
#pragma unroll
                for (int ky = 0; ky < 4; ++ky)
#pragma unroll
                    for (int kx = 0; kx < 4; ++kx)
                        a += xs[dy + ky][2 * px + dx + kx] * wr[ky * 4 + kx];
                m = fmaxf(m, a);
            }
        u16 h = f2bf(m);
        const int o = ((b * 14 + py) * 14 + px) * 256 + t;
        hi[o] = h;
        lo[o] = f2bf(m - bf2f(h));
    }
}

// ---------------- conv2 v2 (proven): 128x128 tile, global_load_lds + XOR-swizzle, split-bf16 3-pass ----------------
// M = 50176, N = 256, K = 16 x 256.  Grid (392, 2), 256 threads (4 waves, each owns 64x64).
__global__ __launch_bounds__(256, 2) void conv2_split_v2(const u16* __restrict__ Ih, const u16* __restrict__ Il,
                                                         const u16* __restrict__ Wh, const u16* __restrict__ Wl,
                                                         const u16* __restrict__ zg,
                                                         const float* __restrict__ bias, float* __restrict__ out) {
    __shared__ __align__(16) short lds[32768];          // AH 0, AL 8192, BH 16384, BL 24576 (64 KiB)
    const int AL = 8192, BH = 16384, BL = 24576;
    const int t = threadIdx.x, lane = t & 63, w = t >> 6;
    const int wm = w >> 1, wn = w & 1;
    const int l16 = lane & 15, l4 = lane >> 4;
    const int m0 = blockIdx.x * 128, n0 = blockIdx.y * 128;
    const int rl = lane >> 3;
    const int chS = (((lane & 7) ^ rl)) << 3;
    int ay[4], ax[4], ab[4], wb[4], aoff[4];
    bool av[4];
#pragma unroll
    for (int j = 0; j < 4; ++j) {
        const int r = w * 32 + j * 8 + rl;
        const int gm = m0 + r;
        const int b = gm / 196, rem = gm % 196;
        ay[j] = rem / 14; ax[j] = rem % 14; ab[j] = b * 196;
        wb[j] = (n0 + r) << 8;
    }
    f32x4 acc[4][4] = {};

    for (int kt = 0; kt < 64; ++kt) {
        const int kk = kt >> 2;
        if ((kt & 3) == 0) {
            const int ky = kk >> 2, kx = kk & 3;
#pragma unroll
            for (int j = 0; j < 4; ++j) {
                const int iy = ay[j] + ky - 1, ix = ax[j] + kx - 1;
                av[j] = ((unsigned)iy < 14u) && ((unsigned)ix < 14u);
                aoff[j] = (ab[j] + iy * 14 + ix) << 8;
            }
        }
        const int kc = (kt & 3) << 6;
        __syncthreads();
#pragma unroll
        for (int j = 0; j < 4; ++j) {
            const int rowb = (w * 32 + j * 8) << 6;
            const u16* gh = av[j] ? (Ih + aoff[j] + kc + chS) : zg;
            const u16* gl = av[j] ? (Il + aoff[j] + kc + chS) : zg;
            gl_lds16(gh, lds + rowb);
            gl_lds16(gl, lds + AL + rowb);
            const int woff = (kk << 16) + wb[j] + kc + chS;
            gl_lds16(Wh + woff, lds + BH + rowb);
            gl_lds16(Wl + woff, lds + BL + rowb);
        }
        __syncthreads();
#pragma unroll
        for (int ks = 0; ks < 2; ++ks) {
            short8 bhf[4], blf[4];
#pragma unroll
            for (int ni = 0; ni < 4; ++ni) {
                const int row = wn * 64 + ni * 16 + l16;
                const int p = (ks * 4 + l4) ^ (row & 7);
                const int off = (row << 6) + (p << 3);
                bhf[ni] = *(const short8*)&lds[BH + off];
                blf[ni] = *(const short8*)&lds[BL + off];
            }
#pragma unroll
            for (int mi = 0; mi < 4; ++mi) {
                const int row = wm * 64 + mi * 16 + l16;
                const int p = (ks * 4 + l4) ^ (row & 7);
                const int off = (row << 6) + (p << 3);
                const short8 ah = *(const short8*)&lds[off];
                const short8 al = *(const short8*)&lds[AL + off];
#pragma unroll
                for (int ni = 0; ni < 4; ++ni) {
                    acc[mi][ni] = __builtin_amdgcn_mfma_f32_16x16x32_bf16(ah, bhf[ni], acc[mi][ni], 0, 0, 0);
                    acc[mi][ni] = __builtin_amdgcn_mfma_f32_16x16x32_bf16(ah, blf[ni], acc[mi][ni], 0, 0, 0);
                    acc[mi][ni] = __builtin_amdgcn_mfma_f32_16x16x32_bf16(al, bhf[ni], acc[mi][ni], 0, 0, 0);
                }
            }
        }
    }
#pragma unroll
    for (int ni = 0; ni < 4; ++ni) {
        const int col = n0 + wn * 64 + ni * 16 + l16;
        const float bv = bias[col];
#pragma unroll
        for (int mi = 0; mi < 4; ++mi) {
            const int mrow = m0 + wm * 64 + mi * 16 + l4 * 4;
#pragma unroll
            for (int r = 0; r < 4; ++r)
                out[(size_t)(mrow + r) * 256 + col] = fmaxf(acc[mi][ni][r] + bv, 0.f);
        }
    }
}

// ---------------- deconv1 parity GEMM v5: v2-style sync-stage-sync single buffer (32KB LDS) ----------------
// M=25088, N=256, K=ntaps(p)x256. Grid (196, 2, 4). Output to upsampled 14x14 grid (2Y+dy, 2X+dx).
__global__ __launch_bounds__(256, 2) void deconv1_par_v5(const _Float16* __restrict__ I,
                                                         const _Float16* __restrict__ WC,
                                                         const _Float16* __restrict__ zg,
                                                         const float* __restrict__ bias,
                                                         _Float16* __restrict__ out) {
    __shared__ __align__(16) _Float16 lds[16384];       // 32KB: A 8192 | B 8192 halfs
    const int t = threadIdx.x, lane = t & 63, w = t >> 6;
    const int wm = w >> 1, wn = w & 1;
    const int l16 = lane & 15, l4 = lane >> 4;
    const int m0 = blockIdx.x * 128, n0 = blockIdx.y * 128;
    const int p = blockIdx.z, dy = p >> 1, dx = p & 1;
    const int nx = 3 - dx;
    const int ntaps = (3 - dy) * nx;
    const int pbase = (dy == 0) ? (dx == 0 ? 0 : 9) : (dx == 0 ? 15 : 21);
    const int nkt = ntaps * 4;

    const int rl8 = lane >> 3;
    const int g = (lane & 7) ^ rl8;
    const _Float16* selA = I + (g << 3);
    const _Float16* selB = WC + ((size_t)pbase << 16) + (g << 3);

    int aY[4], aX[4], ab[4], wb[4];
#pragma unroll
    for (int j = 0; j < 4; ++j) {
        const int r = w * 32 + j * 8 + rl8;
        const int gm = m0 + r;
        const int b = gm / 49, rem = gm % 49;
        aY[j] = rem / 7; aX[j] = rem % 7; ab[j] = b * 49;
        wb[j] = (n0 + r) << 8;
    }
    int aoff[4]; bool av[4];
    auto dectap = [&](int kk) {
        const int oy = kk / nx - (dy == 0 ? 1 : 0);
        const int ox = kk % nx - (dx == 0 ? 1 : 0);
#pragma unroll
        for (int j = 0; j < 4; ++j) {
            const int iy = aY[j] + oy, ix = aX[j] + ox;
            av[j] = ((unsigned)iy < 7u) && ((unsigned)ix < 7u);
            aoff[j] = (ab[j] + iy * 7 + ix) << 8;
        }
    };
    int rdA[4], rdB[4];
#pragma unroll
    for (int mi = 0; mi < 4; ++mi) {
        const int ra = wm * 64 + mi * 16 + l16;
        rdA[mi] = (ra << 6) + ((l4 ^ (ra & 7)) << 3);
    }
#pragma unroll
    for (int ni = 0; ni < 4; ++ni) {
        const int rb = wn * 64 + ni * 16 + l16;
        rdB[ni] = 8192 + (rb << 6) + ((l4 ^ (rb & 7)) << 3);
    }

    f32x4 acc[4][4] = {};
    for (int kt = 0; kt < nkt; ++kt) {
        if ((kt & 3) == 0) dectap(kt >> 2);
        const int kk = kt >> 2, kc = (kt & 3) << 6;
        __syncthreads();
#pragma unroll
        for (int j = 0; j < 4; ++j) {
            const int rowb = (w * 32 + j * 8) << 6;
            const _Float16* asrc = av[j] ? (selA + aoff[j] + kc) : zg;
            gl_lds16(asrc, lds + rowb);
            gl_lds16(selB + (kk << 16) + wb[j] + kc, lds + 8192 + rowb);
        }
        __syncthreads();
#pragma unroll
        for (int ks = 0; ks < 2; ++ks) {
            const int x32 = ks << 5;
            half8 b8[4];
#pragma unroll
            for (int ni = 0; ni < 4; ++ni)
                b8[ni] = *(const half8*)&lds[rdB[ni] ^ x32];
#pragma unroll
            for (int mi = 0; mi < 4; ++mi) {
                const half8 a8 = *(const half8*)&lds[rdA[mi] ^ x32];
#pragma unroll
                for (int ni = 0; ni < 4; ++ni)
                    acc[mi][ni] = __builtin_amdgcn_mfma_f32_16x16x32_f16(a8, b8[ni], acc[mi][ni], 0, 0, 0);
            }
        }
    }
#pragma unroll
    for (int mi = 0; mi < 4; ++mi) {
        const int mb = m0 + wm * 64 + mi * 16 + l4 * 4;
#pragma unroll
        for (int r = 0; r < 4; ++r) {
            const int m = mb + r;
            const int b = m / 49, rem = m % 49;
            const int Y = rem / 7, X = rem % 7;
            _Float16* op = out + (((size_t)(b * 196 + (2 * Y + dy) * 14 + (2 * X + dx))) << 8);
#pragma unroll
            for (int ni = 0; ni < 4; ++ni) {
                const int col = n0 + wn * 64 + ni * 16 + l16;
                op[col] = (_Float16)fmaxf(acc[mi][ni][r] + bias[col], 0.f);
            }
        }
    }
}

// ---------------- encoder stage 1 with fused 2x2 maxpool: 98 k-slices, ew read once ----------------
__global__ __launch_bounds__(256) void encp_v2(const float* __restrict__ h2, const float* __restrict__ ew,
                                               float* __restrict__ partials) {
    __shared__ float ews[8192];                         // [128 k][64 n]
    __shared__ float hbuf[8][128];
    const int t = threadIdx.x, c = blockIdx.x;          // slice c: pooled pixel p0=c>>1, channels (c&1)*128..
    const float* esrc = ew + (size_t)c * 8192;
    for (int i = t; i < 2048; i += 256)
        *(f32x4*)&ews[i * 4] = *(const f32x4*)&esrc[i * 4];
    const int p0 = c >> 1, chb = (c & 1) << 7;
    const int py = p0 / 7, px = p0 % 7;
    const int n = t & 63, sub = t >> 6;
    const int rr = t >> 5, kq = (t & 31) << 2;
    float* pout = partials + (size_t)c * 16384;
    for (int bi = 0; bi < 32; ++bi) {
        const int b = bi * 8 + rr;
        const float* hb = h2 + (((size_t)(b * 14 + 2 * py)) * 14 + 2 * px) * 256 + chb + kq;
        __syncthreads();
        f32x4 v0 = *(const f32x4*)hb;
        f32x4 v1 = *(const f32x4*)(hb + 256);
        f32x4 v2 = *(const f32x4*)(hb + 14 * 256);
        f32x4 v3 = *(const f32x4*)(hb + 14 * 256 + 256);
        f32x4 vm;
#pragma unroll
        for (int q = 0; q < 4; ++q)
            vm[q] = fmaxf(fmaxf(v0[q], v1[q]), fmaxf(v2[q], v3[q]));
        *(f32x4*)&hbuf[rr][kq] = vm;
        __syncthreads();
        float a0 = 0.f, a1 = 0.f;
        for (int k = 0; k < 128; ++k) {
            const float wv = ews[k * 64 + n];
            a0 += hbuf[sub][k] * wv;
            a1 += hbuf[sub + 4][k] * wv;
        }
        pout[(bi * 8 + sub) * 64 + n] = a0;
        pout[(bi * 8 + sub + 4) * 64 + n] = a1;
    }
}

// ---------------- SOM v2: reduce partials + bias -> z_e; argmin; write z_e and z_q into zcat ----------------
__global__ __launch_bounds__(256) void som_v2(const float* __restrict__ partials, const float* __restrict__ eb,
                                              const float* __restrict__ emb, float* __restrict__ zcat) {
    __shared__ float zrow[64];
    __shared__ float sd[256];
    __shared__ int si[256];
    const int b = blockIdx.x, t = threadIdx.x;
    if (t < 64) {
        float s = eb[t];
        const float* p = partials + b * 64 + t;
        for (int c = 0; c < 98; ++c) s += p[(size_t)c * 16384];
        zrow[t] = s;
        zcat[b * 64 + t] = s;
    }
    __syncthreads();
    float acc = 0.f;
    const float* e = emb + t * 64;
    for (int d = 0; d < 64; ++d) { float df = zrow[d] - e[d]; acc += df * df; }
    sd[t] = acc; si[t] = t;
    __syncthreads();
    for (int off = 128; off >= 1; off >>= 1) {
        if (t < off) {
            float d2 = sd[t + off]; int i2 = si[t + off];
            if (d2 < sd[t] || (d2 == sd[t] && i2 < si[t])) { sd[t] = d2; si[t] = i2; }
        }
        __syncthreads();
    }
    const int k = si[0];
    if (t < 64) zcat[(256 + b) * 64 + t] = emb[k * 64 + t];
}

// ---------------- decoder linear ----------------
__global__ __launch_bounds__(256) void dec_kernel(const float* __restrict__ zcat, const float* __restrict__ dw,
                                                  const float* __restrict__ db, _Float16* __restrict__ dech) {
    __shared__ float z[8][64];
    const int t = threadIdx.x;
    const int bg = blockIdx.x / 49;
    const int nc = blockIdx.x % 49;
    for (int i = t; i < 512; i += 256) z[i >> 6][i & 63] = zcat[bg * 512 + i];
    __syncthreads();
    const int n = nc * 256 + t;
    const float bv = db[n];
    float acc[8];
#pragma unroll
    for (int j = 0; j < 8; ++j) acc[j] = bv;
    for (int k = 0; k < 64; ++k) {
        float wv = dw[(size_t)k * 12544 + n];
#pragma unroll
        for (int j = 0; j < 8; ++j) acc[j] += z[j][k] * wv;
    }
#pragma unroll
    for (int j = 0; j < 8; ++j) dech[((size_t)(bg * 8 + j)) * 12544 + n] = (_Float16)acc[j];
}

// ---------------- deconv2 v6: quarter-image blocks, weights in LDS, sigmoid ----------------
__global__ __launch_bounds__(256) void deconv2_v6(const _Float16* __restrict__ d1, const _Float16* __restrict__ w2c,
                                                  const float* __restrict__ bias, float* __restrict__ out) {
    __shared__ _Float16 ds[6 * 14 * 256];               // 42KB input rows
    __shared__ _Float16 wl[9216];                       // 18KB [p][9][256] weights (LDS: runtime-indexable)
    const int t = threadIdx.x;
    const int blk = blockIdx.x;                         // 512 b x 4 quarters
    const int q = blk & 3, b = blk >> 2;
    const int r0 = (q == 3) ? 8 : 3 * q;
    for (int i = t; i < 1152; i += 256)
        *(half8*)&wl[i * 8] = *(const half8*)&w2c[i * 8];
    for (int i = t; i < 2688; i += 256) {
        const int r = i / 448, rem = i % 448;
        *(half8*)&ds[r * 3584 + rem * 8] =
            *(const half8*)&d1[((size_t)(b * 14 + r0 + r) * 14) * 256 + rem * 8];
    }
    const int lane = t & 63, wv = t >> 6;
    const int ch0 = lane * 4;
    const float bv = bias[0];
    __syncthreads();
    for (int pi = 0; pi < 49; ++pi) {
        const int ql = pi * 4 + wv;
        const int oy = 7 * q + ql / 28, ox = ql % 28;
        const int dy = oy & 1, Y = oy >> 1;
        const int dxp = ox & 1, X = ox >> 1;
        const _Float16* wp = &wl[((dy * 2 + dxp) * 9) * 256 + ch0];
        float a0 = 0.f, a1 = 0.f;
#pragma unroll
        for (int j = 0; j < 9; ++j) {
            const int iy = Y + (j / 3) - (dy ? 0 : 1);
            const int ix = X + (j % 3) - (dxp ? 0 : 1);
            if (iy >= r0 && iy < r0 + 6 && (unsigned)ix < 14u) {
                const half4 dv = *(const half4*)&ds[((iy - r0) * 14 + ix) * 256 + ch0];
                const half4 w4 = *(const half4*)&wp[j * 256];
                half2v dlo = {dv.x, dv.y}, dhi = {dv.z, dv.w};
                half2v wlo = {w4.x, w4.y}, whi = {w4.z, w4.w};
                a0 = __builtin_amdgcn_fdot2(dlo, wlo, a0, false);
                a1 = __builtin_amdgcn_fdot2(dhi, whi, a1, false);
            }
        }
        float acc = a0 + a1;
#pragma unroll
        for (int off = 32; off; off >>= 1) acc += __shfl_xor(acc, off);
        if (lane == 0) out[(size_t)b * 784 + oy * 28 + ox] = 1.f / (1.f + expf(-(acc + bv)));
    }
}

extern "C" void kernel_launch(void* const* d_in, const int* in_sizes, int n_in,
                              void* d_out, int out_size, void* d_ws, size_t ws_size,
                              hipStream_t stream) {
    const float* x    = (const float*)d_in[0];
    const float* c1w  = (const float*)d_in[1];
    const float* c1b  = (const float*)d_in[2];
    const float* c2w  = (const float*)d_in[3];
    const float* c2b  = (const float*)d_in[4];
    const float* ew   = (const float*)d_in[5];
    const float* eb   = (const float*)d_in[6];
    const float* emb  = (const float*)d_in[7];
    const float* dw   = (const float*)d_in[8];
    const float* db   = (const float*)d_in[9];
    const float* dc1w = (const float*)d_in[10];
    const float* dc1b = (const float*)d_in[11];
    const float* dc2w = (const float*)d_in[12];
    const float* dc2b = (const float*)d_in[13];
    float* out = (float*)d_out;

    char* ws = (char*)d_ws;
    size_t off = 0;
    auto alloc = [&](size_t bytes) { size_t o = off; off += (bytes + 255) & ~(size_t)255; return o; };

    u16*      h1p_hi   = (u16*)(ws + alloc((size_t)256 * 196 * 256 * 2));
    u16*      h1p_lo   = (u16*)(ws + alloc((size_t)256 * 196 * 256 * 2));
    u16*      w2T_hi   = (u16*)(ws + alloc((size_t)16 * 256 * 256 * 2));
    u16*      w2T_lo   = (u16*)(ws + alloc((size_t)16 * 256 * 256 * 2));
    float*    h2       = (float*)(ws + alloc((size_t)256 * 196 * 256 * 4));
    float*    partials = (float*)(ws + alloc((size_t)98 * 16384 * 4));
    float*    zcat     = (float*)(ws + alloc((size_t)512 * 64 * 4));
    _Float16* dech     = (_Float16*)(ws + alloc((size_t)512 * 49 * 256 * 2));
    _Float16* wc1      = (_Float16*)(ws + alloc((size_t)25 * 256 * 256 * 2));
    _Float16* d1       = (_Float16*)(ws + alloc((size_t)512 * 196 * 256 * 2));
    _Float16* w2c      = (_Float16*)(ws + alloc((size_t)9216 * 2));
    u16*      zg       = (u16*)(ws + alloc(256));

    wprep_all<<<10533, 256, 0, stream>>>(c2w, w2T_hi, w2T_lo, dc1w, wc1, dc2w, w2c, zg);
    conv1_pool_v2<<<3584, 256, 0, stream>>>(x, c1w, c1b, h1p_hi, h1p_lo);
    conv2_split_v2<<<dim3(392, 2), 256, 0, stream>>>(h1p_hi, h1p_lo, w2T_hi, w2T_lo, zg, c2b, h2);
    encp_v2<<<98, 256, 0, stream>>>(h2, ew, partials);
    som_v2<<<256, 256, 0, stream>>>(partials, eb, emb, zcat);
    dec_kernel<<<3136, 256, 0, stream>>>(zcat, dw, db, dech);
    deconv1_par_v5<<<dim3(196, 2, 4), 256, 0, stream>>>(dech, wc1, (const _Float16*)zg, dc1b, d1);
    deconv2_v6<<<2048, 256, 0, stream>>>(d1, w2c, dc2b, out);
}